// Round 14
// baseline (275.075 us; speedup 1.0000x reference)
//
#include <hip/hip_runtime.h>
#include <hip/hip_bf16.h>

typedef __bf16 bf16x8 __attribute__((ext_vector_type(8)));
typedef float f32x4 __attribute__((ext_vector_type(4)));

static __device__ __forceinline__ __bf16 tobf(float x) {
    __hip_bfloat16 h = __float2bfloat16(x);
    __bf16 r;
    __builtin_memcpy(&r, &h, 2);
    return r;
}

// fast 2^x: single v_exp_f32 (no libm range-fixup code)
static __device__ __forceinline__ float fexp2(float x) {
    float r;
    asm("v_exp_f32 %0, %1" : "=v"(r) : "v"(x));
    return r;
}

// ---------------------------------------------------------------------------
// Fused prep: (a) x fp32 -> bf16 (vectorized), (b) W_attn^T with qscale
// folded into Q columns, (c) W_proj^T.  One launch instead of three.
// ---------------------------------------------------------------------------
__global__ __launch_bounds__(256) void prep_k(const float* __restrict__ x,
                                              __hip_bfloat16* __restrict__ x_bf,
                                              const float* __restrict__ Wa,
                                              __hip_bfloat16* __restrict__ WaT,
                                              const float* __restrict__ Wp,
                                              __hip_bfloat16* __restrict__ WpT) {
    __shared__ float tile[32][33];
    const int bid = blockIdx.x;
    const int tid = threadIdx.x;
    if (bid < 8192) {
        int i = bid * 256 + tid;
        float4 v = reinterpret_cast<const float4*>(x)[i];
        __hip_bfloat16 a = __float2bfloat16(v.x);
        __hip_bfloat16 b = __float2bfloat16(v.y);
        __hip_bfloat16 c = __float2bfloat16(v.z);
        __hip_bfloat16 d = __float2bfloat16(v.w);
        ushort4 o;
        o.x = *reinterpret_cast<unsigned short*>(&a);
        o.y = *reinterpret_cast<unsigned short*>(&b);
        o.z = *reinterpret_cast<unsigned short*>(&c);
        o.w = *reinterpret_cast<unsigned short*>(&d);
        reinterpret_cast<ushort4*>(x_bf)[i] = o;
        return;
    }
    const float* in;
    __hip_bfloat16* out;
    int bx, Cn, qrows;
    float qscale;
    int t;
    if (bid < 8192 + 3072) {
        t = bid - 8192;
        in = Wa; out = WaT; Cn = 3072; qrows = 1024;
        qscale = 0.045084223f;  // log2(e)/sqrt(1024)
        bx = t % 96;
    } else {
        t = bid - 11264;
        in = Wp; out = WpT; Cn = 1024; qrows = 0;
        qscale = 1.0f;
        bx = t % 32;
    }
    const int by = (bid < 11264) ? (t / 96) : (t / 32);
    const int R = 1024;
    const int c0 = bx * 32, r0 = by * 32;
    const int tx = tid & 31, ty = tid >> 5;  // 32 x 8
#pragma unroll
    for (int i = 0; i < 4; ++i)
        tile[ty + i * 8][tx] = in[(size_t)(r0 + ty + i * 8) * Cn + c0 + tx];
    __syncthreads();
#pragma unroll
    for (int i = 0; i < 4; ++i) {
        int orow = c0 + ty + i * 8;
        float v = tile[tx][ty + i * 8];
        if (orow < qrows) v *= qscale;
        out[(size_t)orow * R + r0 + tx] = __float2bfloat16(v);
    }
}

// ---------------------------------------------------------------------------
// V transpose + key-permute: qkv V-section [b][t][h*64+d] ->
// Vt[(b*16+h)*64+d][slot(t)], slot(r) = ((r&12)<<1)|(r&3)|((r>>4)<<2) within
// each 32-key block. Matches the register layout of swapped-QK^T P frags so
// the PV A-operand is a pure register pack.
// ---------------------------------------------------------------------------
__global__ __launch_bounds__(256) void vtrans_k(const __hip_bfloat16* __restrict__ qkv,
                                                __hip_bfloat16* __restrict__ Vt) {
    __shared__ __hip_bfloat16 tile[32][33];
    const int bh = blockIdx.z, b = bh >> 4, h = bh & 15;
    const int tt = blockIdx.x;  // 0..63 (t tile)
    const int dt = blockIdx.y;  // 0..1  (d tile)
    const int tx = threadIdx.x & 31, ty = threadIdx.x >> 5;  // 32 x 8
    const __hip_bfloat16* src = qkv + (size_t)b * 2048 * 3072 + 2048 + h * 64;
#pragma unroll
    for (int i = 0; i < 4; ++i)
        tile[ty + i * 8][tx] = src[(size_t)(tt * 32 + ty + i * 8) * 3072 + dt * 32 + tx];
    __syncthreads();
    const int slot = ((tx & 12) << 1) | (tx & 3) | ((tx >> 4) << 2);
    __hip_bfloat16* dst = Vt + ((size_t)bh * 64 + dt * 32) * 2048 + tt * 32;
#pragma unroll
    for (int i = 0; i < 4; ++i)
        dst[(size_t)(ty + i * 8) * 2048 + slot] = tile[tx][ty + i * 8];
}

// ---------------------------------------------------------------------------
// bf16 GEMM, C = A[M][K] * B, with B given transposed: Bt[N][K].
// m97 structure: 128x128 tile, BK=32, 4 waves each owning 64x64.
// XCD-aware tile swizzle (grid size divisible by 8).
// ---------------------------------------------------------------------------
template <bool OUT_BF16>
__global__ __launch_bounds__(256) void gemm_bt(const __hip_bfloat16* __restrict__ A,
                                               const __hip_bfloat16* __restrict__ Bt,
                                               __hip_bfloat16* __restrict__ Cb,
                                               float* __restrict__ Cf,
                                               int M, int N, int K) {
    __shared__ __attribute__((aligned(16))) __hip_bfloat16 As[128 * 32];
    __shared__ __attribute__((aligned(16))) __hip_bfloat16 Bs[128 * 32];
    const int tid = threadIdx.x;
    const int lane = tid & 63, wid = tid >> 6;
    const int l15 = lane & 15, lg = lane >> 4;
    const int wr = wid >> 1, wc = wid & 1;
    const int lin = blockIdx.y * gridDim.x + blockIdx.x;
    const int cpx = (gridDim.x * gridDim.y) >> 3;
    const int sw = (lin & 7) * cpx + (lin >> 3);
    const int bn = sw % gridDim.x, bm = sw / gridDim.x;
    const size_t arow0 = (size_t)bm * 128;
    const size_t brow0 = (size_t)bn * 128;

    f32x4 acc[4][4] = {};

    const int nk = K >> 5;
    for (int kt = 0; kt < nk; ++kt) {
        __syncthreads();
        {
            const int k0 = kt * 32;
#pragma unroll
            for (int p = 0; p < 2; ++p) {
                int idx = p * 256 + tid;
                int row = idx >> 2;
                int cc = (idx & 3) * 8;
                const __hip_bfloat16* ga = A + (arow0 + row) * (size_t)K + k0 + cc;
                const __hip_bfloat16* gb = Bt + (brow0 + row) * (size_t)K + k0 + cc;
                __builtin_amdgcn_global_load_lds(
                    (const __attribute__((address_space(1))) void*)ga,
                    (__attribute__((address_space(3))) void*)(&As[idx * 8]), 16, 0, 0);
                __builtin_amdgcn_global_load_lds(
                    (const __attribute__((address_space(1))) void*)gb,
                    (__attribute__((address_space(3))) void*)(&Bs[idx * 8]), 16, 0, 0);
            }
        }
        __syncthreads();
        bf16x8 af[4], bfr[4];
#pragma unroll
        for (int m = 0; m < 4; ++m)
            af[m] = *reinterpret_cast<const bf16x8*>(&As[(wr * 64 + m * 16 + l15) * 32 + lg * 8]);
#pragma unroll
        for (int n = 0; n < 4; ++n)
            bfr[n] = *reinterpret_cast<const bf16x8*>(&Bs[(wc * 64 + n * 16 + l15) * 32 + lg * 8]);
#pragma unroll
        for (int m = 0; m < 4; ++m)
#pragma unroll
            for (int n = 0; n < 4; ++n)
                acc[m][n] = __builtin_amdgcn_mfma_f32_16x16x32_bf16(af[m], bfr[n], acc[m][n], 0, 0, 0);
    }

#pragma unroll
    for (int m = 0; m < 4; ++m) {
#pragma unroll
        for (int n = 0; n < 4; ++n) {
#pragma unroll
            for (int j = 0; j < 4; ++j) {
                int row = bm * 128 + wr * 64 + m * 16 + lg * 4 + j;
                int col = bn * 128 + wc * 64 + n * 16 + l15;
                if (OUT_BF16)
                    Cb[(size_t)row * N + col] = __float2bfloat16(acc[m][n][j]);
                else
                    Cf[(size_t)row * N + col] = acc[m][n][j];
            }
        }
    }
}

// ---------------------------------------------------------------------------
// Flash attention (causal), swapped-QK^T, key-permuted V, MAX-FREE softmax,
// MFMA ROW-SUM, triangle-paired 2-pass blocks, CROSS-ITERATION SOFTWARE
// PIPELINE: 3-buffer LDS rotation for K; next tile's K ds_reads issued at
// iteration top (1 full iteration of slack), next tile's V globals issued
// mid-iteration; counted vmcnt(8) drains only the K-staging loads (V loads
// stay in flight across the barrier). Ping-pong register sets (A/B) keep all
// array indexing compile-time-static.
// ---------------------------------------------------------------------------
__global__ __launch_bounds__(128, 2) void attn_k(const __hip_bfloat16* __restrict__ qkv,
                                                 const __hip_bfloat16* __restrict__ Vt,
                                                 __hip_bfloat16* __restrict__ y) {
    constexpr int TT = 2048;
    constexpr int S3C = 3072;
    const int bh = blockIdx.x, b = bh >> 4, h = bh & 15;
    const int tid = threadIdx.x;
    const int wid = tid >> 6, lane = tid & 63;
    const int l15 = lane & 15, lg = lane >> 4;

    __shared__ __attribute__((aligned(16))) char Ks[3][64 * 128];  // 3 x 8 KB rotation

    const __hip_bfloat16* base = qkv + (size_t)b * TT * S3C;
    const int qo = h * 64, ko = 1024 + h * 64;
    const __hip_bfloat16* vt = Vt + (size_t)bh * 64 * TT;

    // B-fragment of ones for the MFMA row-sum
    bf16x8 vones;
#pragma unroll
    for (int i = 0; i < 8; ++i) vones[i] = tobf(1.0f);

    // stage one 64-key tile (4 x 16B per thread, pre-swizzled source cols)
#define STAGE(BUF, KT)                                                                             \
    do {                                                                                           \
        const int kb_ = (KT) * 64;                                                                 \
        _Pragma("unroll") for (int p_ = 0; p_ < 4; ++p_) {                                         \
            int idx_ = p_ * 128 + tid;                                                             \
            int row_ = idx_ >> 3, c_ = idx_ & 7;                                                   \
            int col_ = 8 * (c_ ^ (row_ & 7));                                                      \
            __builtin_amdgcn_global_load_lds(                                                      \
                (const __attribute__((address_space(1))) void*)(base + (size_t)(kb_ + row_) * S3C + ko + col_), \
                (__attribute__((address_space(3))) void*)(&Ks[BUF][idx_ * 16]), 16, 0, 0);         \
        }                                                                                          \
    } while (0)

#pragma unroll 1
    for (int pass = 0; pass < 2; ++pass) {
        const int qt = pass == 0 ? (31 - (int)blockIdx.y) : (int)blockIdx.y;
        const int qbase = qt * 64 + wid * 32;
        const int nt = qt + 1;
        const int sw = l15 & 7;

        // Q B-fragments (pre-scaled by log2e/sqrt(C)): [m][half]
        bf16x8 aq[2][2];
#pragma unroll
        for (int m = 0; m < 2; ++m) {
            const __hip_bfloat16* qp = base + (size_t)(qbase + m * 16 + l15) * S3C + qo + lg * 8;
            aq[m][0] = *reinterpret_cast<const bf16x8*>(qp);
            aq[m][1] = *reinterpret_cast<const bf16x8*>(qp + 32);
        }

        f32x4 acc[2][4] = {};  // [m][dg]: row=q(lg*4+j), col=d(dg*16+l15)
        f32x4 lsum[2] = {};    // MFMA row-sums, same row layout as acc

        bf16x8 kfA[4][2], kfB[4][2];  // ping-pong K fragment sets
        bf16x8 vbA[2][4], vbB[2][4];  // ping-pong V fragment sets

        // ---- prologue: stage tiles 0,1; preload set A (tile 0: K frags + V)
        STAGE(0, 0);
        STAGE(1, nt > 1 ? 1 : 0);
        asm volatile("s_waitcnt vmcnt(0)" ::: "memory");
        __syncthreads();
        {
            const char* Kb = &Ks[0][0];
#pragma unroll
            for (int cg = 0; cg < 4; ++cg) {
                const char* krow = Kb + (cg * 16 + l15) * 128;
                kfA[cg][0] = *reinterpret_cast<const bf16x8*>(krow + 16 * (lg ^ sw));
                kfA[cg][1] = *reinterpret_cast<const bf16x8*>(krow + 16 * ((4 + lg) ^ sw));
            }
#pragma unroll
            for (int dg = 0; dg < 4; ++dg) {
                const __hip_bfloat16* vrow = vt + (size_t)(dg * 16 + l15) * TT + lg * 8;
                vbA[0][dg] = *reinterpret_cast<const bf16x8*>(vrow);
                vbA[1][dg] = *reinterpret_cast<const bf16x8*>(vrow + 32);
            }
        }

        // one pipelined iteration: compute tile kt from (kfc, vbc); load tile
        // kt+1 into (kfn, vbn); stage tile kt+2 into Ks[bstg].
        auto step = [&](bf16x8 (&kfc)[4][2], bf16x8 (&vbc)[2][4],
                        bf16x8 (&kfn)[4][2], bf16x8 (&vbn)[2][4],
                        int kt, int bnxt, int bstg) {
            const int kb = kt * 64;
            // 1. next-tile K fragments from LDS (staged last iteration)
            if (kt + 1 < nt) {
                const char* Kb = &Ks[bnxt][0];
#pragma unroll
                for (int cg = 0; cg < 4; ++cg) {
                    const char* krow = Kb + (cg * 16 + l15) * 128;
                    kfn[cg][0] = *reinterpret_cast<const bf16x8*>(krow + 16 * (lg ^ sw));
                    kfn[cg][1] = *reinterpret_cast<const bf16x8*>(krow + 16 * ((4 + lg) ^ sw));
                }
            }
            // 2. stage tile kt+2 (async global -> LDS)
            if (kt + 2 < nt) STAGE(bstg, kt + 2);
            __builtin_amdgcn_sched_barrier(0);  // pin: stage loads issue before V loads
            // 3. QK^T (swapped) from current K frags
            f32x4 s[2][4];
            __builtin_amdgcn_s_setprio(1);
#pragma unroll
            for (int cg = 0; cg < 4; ++cg)
#pragma unroll
                for (int m = 0; m < 2; ++m) {
                    f32x4 z = {0.f, 0.f, 0.f, 0.f};
                    z = __builtin_amdgcn_mfma_f32_16x16x32_bf16(kfc[cg][0], aq[m][0], z, 0, 0, 0);
                    z = __builtin_amdgcn_mfma_f32_16x16x32_bf16(kfc[cg][1], aq[m][1], z, 0, 0, 0);
                    s[m][cg] = z;
                }
            __builtin_amdgcn_s_setprio(0);
            // 4. next-tile V fragments (global; land during next iteration)
            if (kt + 1 < nt) {
                const int kb2 = kb + 64;
#pragma unroll
                for (int dg = 0; dg < 4; ++dg) {
                    const __hip_bfloat16* vrow = vt + (size_t)(dg * 16 + l15) * TT + kb2 + lg * 8;
                    vbn[0][dg] = *reinterpret_cast<const bf16x8*>(vrow);
                    vbn[1][dg] = *reinterpret_cast<const bf16x8*>(vrow + 32);
                }
            }
            // 5. max-free softmax: p = 2^s (masked -> 0)
            float p[2][4][4];
            const bool needmask = (kb + 63 > qbase);
#pragma unroll
            for (int m = 0; m < 2; ++m)
#pragma unroll
                for (int cg = 0; cg < 4; ++cg)
#pragma unroll
                    for (int j = 0; j < 4; ++j) {
                        float e = fexp2(s[m][cg][j]);
                        if (needmask) {
                            int key = kb + cg * 16 + lg * 4 + j;
                            int qrow = qbase + m * 16 + l15;
                            e = (key > qrow) ? 0.f : e;
                        }
                        p[m][cg][j] = e;
                    }
            // 6. P A-frags: pure register pack (key-permutation baked into Vt)
            bf16x8 pa[2][2];
#pragma unroll
            for (int m = 0; m < 2; ++m)
#pragma unroll
                for (int ks = 0; ks < 2; ++ks) {
                    bf16x8 t;
                    t[0] = tobf(p[m][2 * ks][0]);
                    t[1] = tobf(p[m][2 * ks][1]);
                    t[2] = tobf(p[m][2 * ks][2]);
                    t[3] = tobf(p[m][2 * ks][3]);
                    t[4] = tobf(p[m][2 * ks + 1][0]);
                    t[5] = tobf(p[m][2 * ks + 1][1]);
                    t[6] = tobf(p[m][2 * ks + 1][2]);
                    t[7] = tobf(p[m][2 * ks + 1][3]);
                    pa[m][ks] = t;
                }
            // 7. PV + MFMA row-sum from current V frags (loaded last iteration)
            __builtin_amdgcn_s_setprio(1);
#pragma unroll
            for (int ks = 0; ks < 2; ++ks) {
#pragma unroll
                for (int dg = 0; dg < 4; ++dg)
#pragma unroll
                    for (int m = 0; m < 2; ++m)
                        acc[m][dg] = __builtin_amdgcn_mfma_f32_16x16x32_bf16(pa[m][ks], vbc[ks][dg],
                                                                             acc[m][dg], 0, 0, 0);
#pragma unroll
                for (int m = 0; m < 2; ++m)
                    lsum[m] = __builtin_amdgcn_mfma_f32_16x16x32_bf16(pa[m][ks], vones,
                                                                      lsum[m], 0, 0, 0);
            }
            __builtin_amdgcn_s_setprio(0);
            // 8. drain only the K-staging loads (V loads remain in flight)
            asm volatile("s_waitcnt vmcnt(8)" ::: "memory");
            __syncthreads();
        };

        int kt = 0, bcur = 0, bnxt = 1, bstg = 2;
#pragma unroll 1
        while (kt < nt) {
            step(kfA, vbA, kfB, vbB, kt, bnxt, bstg);
            { int t0 = bcur; bcur = bnxt; bnxt = bstg; bstg = t0; }
            ++kt;
            if (kt >= nt) break;
            step(kfB, vbB, kfA, vbA, kt, bnxt, bstg);
            { int t0 = bcur; bcur = bnxt; bnxt = bstg; bstg = t0; }
            ++kt;
        }

        // ---- epilogue: lsum already in acc row layout -> no cross-lane ops
#pragma unroll
        for (int m = 0; m < 2; ++m)
#pragma unroll
            for (int j = 0; j < 4; ++j) {
                float inv = 1.f / lsum[m][j];
                int t = qbase + m * 16 + lg * 4 + j;
#pragma unroll
                for (int dg = 0; dg < 4; ++dg) {
                    float o = acc[m][dg][j] * inv;
                    y[((size_t)(b * TT + t)) * 1024 + h * 64 + dg * 16 + l15] = __float2bfloat16(o);
                }
            }
        // pass isolation: quiesce all outstanding loads before re-staging
        asm volatile("s_waitcnt vmcnt(0)" ::: "memory");
        __syncthreads();
    }
#undef STAGE
}

// ---------------------------------------------------------------------------
extern "C" void kernel_launch(void* const* d_in, const int* in_sizes, int n_in,
                              void* d_out, int out_size, void* d_ws, size_t ws_size,
                              hipStream_t stream) {
    const float* x = (const float*)d_in[0];   // [4,2048,1024]
    const float* Wa = (const float*)d_in[1];  // [1024,3072]
    const float* Wp = (const float*)d_in[2];  // [1024,1024]
    float* out = (float*)d_out;               // [4,2048,1024] fp32

    __hip_bfloat16* ws = (__hip_bfloat16*)d_ws;
    __hip_bfloat16* x_bf = ws;                          // 8192*1024 (dead after GEMM1)
    __hip_bfloat16* WaT = x_bf + (size_t)8192 * 1024;   // 3072*1024 (W_attn^T)
    __hip_bfloat16* WpT = WaT + (size_t)3072 * 1024;    // 1024*1024 (W_proj^T)
    __hip_bfloat16* qkv = WpT + (size_t)1024 * 1024;    // 8192*3072
    __hip_bfloat16* ybf = qkv + (size_t)8192 * 3072;    // 8192*1024
    __hip_bfloat16* Vt = x_bf;                          // reuse: 64*64*2048 = 8192*1024

    // fused prep: x cvt + W_attn^T (Q cols scaled by log2e/sqrt(C)) + W_proj^T
    prep_k<<<8192 + 3072 + 1024, 256, 0, stream>>>(x, x_bf, Wa, WaT, Wp, WpT);
    // qkv = x @ W_attn   (M=8192, N=3072, K=1024)
    gemm_bt<true><<<dim3(24, 64), 256, 0, stream>>>(x_bf, WaT, qkv, nullptr, 8192, 3072, 1024);
    // V^T per head, key-permuted (x_bf is dead now; Vt aliases it)
    vtrans_k<<<dim3(64, 2, 64), 256, 0, stream>>>(qkv, Vt);
    // flash attention -> ybf (triangle-paired 2-pass blocks, sw-pipelined)
    attn_k<<<dim3(64, 16), 128, 0, stream>>>(qkv, Vt, ybf);
    // out = y @ W_proj   (M=8192, N=1024, K=1024), fp32 out
    gemm_bt<false><<<dim3(8, 64), 256, 0, stream>>>(ybf, WpT, nullptr, out, 8192, 1024, 1024);
}

// Round 15
// 183.630 us; speedup vs baseline: 1.4980x; 1.4980x over previous
//
#include <hip/hip_runtime.h>
#include <hip/hip_bf16.h>

typedef __bf16 bf16x8 __attribute__((ext_vector_type(8)));
typedef float f32x4 __attribute__((ext_vector_type(4)));

static __device__ __forceinline__ __bf16 tobf(float x) {
    __hip_bfloat16 h = __float2bfloat16(x);
    __bf16 r;
    __builtin_memcpy(&r, &h, 2);
    return r;
}

// fast 2^x: single v_exp_f32 (no libm range-fixup code)
static __device__ __forceinline__ float fexp2(float x) {
    float r;
    asm("v_exp_f32 %0, %1" : "=v"(r) : "v"(x));
    return r;
}

// ---------------------------------------------------------------------------
// Fused prep: (a) x fp32 -> bf16 (vectorized), (b) W_attn^T with qscale
// folded into Q columns, (c) W_proj^T.  One launch instead of three.
// ---------------------------------------------------------------------------
__global__ __launch_bounds__(256) void prep_k(const float* __restrict__ x,
                                              __hip_bfloat16* __restrict__ x_bf,
                                              const float* __restrict__ Wa,
                                              __hip_bfloat16* __restrict__ WaT,
                                              const float* __restrict__ Wp,
                                              __hip_bfloat16* __restrict__ WpT) {
    __shared__ float tile[32][33];
    const int bid = blockIdx.x;
    const int tid = threadIdx.x;
    if (bid < 8192) {
        int i = bid * 256 + tid;
        float4 v = reinterpret_cast<const float4*>(x)[i];
        __hip_bfloat16 a = __float2bfloat16(v.x);
        __hip_bfloat16 b = __float2bfloat16(v.y);
        __hip_bfloat16 c = __float2bfloat16(v.z);
        __hip_bfloat16 d = __float2bfloat16(v.w);
        ushort4 o;
        o.x = *reinterpret_cast<unsigned short*>(&a);
        o.y = *reinterpret_cast<unsigned short*>(&b);
        o.z = *reinterpret_cast<unsigned short*>(&c);
        o.w = *reinterpret_cast<unsigned short*>(&d);
        reinterpret_cast<ushort4*>(x_bf)[i] = o;
        return;
    }
    const float* in;
    __hip_bfloat16* out;
    int bx, Cn, qrows;
    float qscale;
    int t;
    if (bid < 8192 + 3072) {
        t = bid - 8192;
        in = Wa; out = WaT; Cn = 3072; qrows = 1024;
        qscale = 0.045084223f;  // log2(e)/sqrt(1024)
        bx = t % 96;
    } else {
        t = bid - 11264;
        in = Wp; out = WpT; Cn = 1024; qrows = 0;
        qscale = 1.0f;
        bx = t % 32;
    }
    const int by = (bid < 11264) ? (t / 96) : (t / 32);
    const int R = 1024;
    const int c0 = bx * 32, r0 = by * 32;
    const int tx = tid & 31, ty = tid >> 5;  // 32 x 8
#pragma unroll
    for (int i = 0; i < 4; ++i)
        tile[ty + i * 8][tx] = in[(size_t)(r0 + ty + i * 8) * Cn + c0 + tx];
    __syncthreads();
#pragma unroll
    for (int i = 0; i < 4; ++i) {
        int orow = c0 + ty + i * 8;
        float v = tile[tx][ty + i * 8];
        if (orow < qrows) v *= qscale;
        out[(size_t)orow * R + r0 + tx] = __float2bfloat16(v);
    }
}

// ---------------------------------------------------------------------------
// V transpose + key-permute: qkv V-section [b][t][h*64+d] ->
// Vt[(b*16+h)*64+d][slot(t)], slot(r) = ((r&12)<<1)|(r&3)|((r>>4)<<2) within
// each 32-key block. Matches the register layout of swapped-QK^T P frags so
// the PV A-operand is a pure register pack.
// ---------------------------------------------------------------------------
__global__ __launch_bounds__(256) void vtrans_k(const __hip_bfloat16* __restrict__ qkv,
                                                __hip_bfloat16* __restrict__ Vt) {
    __shared__ __hip_bfloat16 tile[32][33];
    const int bh = blockIdx.z, b = bh >> 4, h = bh & 15;
    const int tt = blockIdx.x;  // 0..63 (t tile)
    const int dt = blockIdx.y;  // 0..1  (d tile)
    const int tx = threadIdx.x & 31, ty = threadIdx.x >> 5;  // 32 x 8
    const __hip_bfloat16* src = qkv + (size_t)b * 2048 * 3072 + 2048 + h * 64;
#pragma unroll
    for (int i = 0; i < 4; ++i)
        tile[ty + i * 8][tx] = src[(size_t)(tt * 32 + ty + i * 8) * 3072 + dt * 32 + tx];
    __syncthreads();
    const int slot = ((tx & 12) << 1) | (tx & 3) | ((tx >> 4) << 2);
    __hip_bfloat16* dst = Vt + ((size_t)bh * 64 + dt * 32) * 2048 + tt * 32;
#pragma unroll
    for (int i = 0; i < 4; ++i)
        dst[(size_t)(ty + i * 8) * 2048 + slot] = tile[tx][ty + i * 8];
}

// ---------------------------------------------------------------------------
// bf16 GEMM, C = A[M][K] * B, with B given transposed: Bt[N][K].
// m97 structure: 128x128 tile, BK=32, 4 waves each owning 64x64.
// XCD-aware tile swizzle (grid size divisible by 8).
// ---------------------------------------------------------------------------
template <bool OUT_BF16>
__global__ __launch_bounds__(256) void gemm_bt(const __hip_bfloat16* __restrict__ A,
                                               const __hip_bfloat16* __restrict__ Bt,
                                               __hip_bfloat16* __restrict__ Cb,
                                               float* __restrict__ Cf,
                                               int M, int N, int K) {
    __shared__ __attribute__((aligned(16))) __hip_bfloat16 As[128 * 32];
    __shared__ __attribute__((aligned(16))) __hip_bfloat16 Bs[128 * 32];
    const int tid = threadIdx.x;
    const int lane = tid & 63, wid = tid >> 6;
    const int l15 = lane & 15, lg = lane >> 4;
    const int wr = wid >> 1, wc = wid & 1;
    const int lin = blockIdx.y * gridDim.x + blockIdx.x;
    const int cpx = (gridDim.x * gridDim.y) >> 3;
    const int sw = (lin & 7) * cpx + (lin >> 3);
    const int bn = sw % gridDim.x, bm = sw / gridDim.x;
    const size_t arow0 = (size_t)bm * 128;
    const size_t brow0 = (size_t)bn * 128;

    f32x4 acc[4][4] = {};

    const int nk = K >> 5;
    for (int kt = 0; kt < nk; ++kt) {
        __syncthreads();
        {
            const int k0 = kt * 32;
#pragma unroll
            for (int p = 0; p < 2; ++p) {
                int idx = p * 256 + tid;
                int row = idx >> 2;
                int cc = (idx & 3) * 8;
                const __hip_bfloat16* ga = A + (arow0 + row) * (size_t)K + k0 + cc;
                const __hip_bfloat16* gb = Bt + (brow0 + row) * (size_t)K + k0 + cc;
                __builtin_amdgcn_global_load_lds(
                    (const __attribute__((address_space(1))) void*)ga,
                    (__attribute__((address_space(3))) void*)(&As[idx * 8]), 16, 0, 0);
                __builtin_amdgcn_global_load_lds(
                    (const __attribute__((address_space(1))) void*)gb,
                    (__attribute__((address_space(3))) void*)(&Bs[idx * 8]), 16, 0, 0);
            }
        }
        __syncthreads();
        bf16x8 af[4], bfr[4];
#pragma unroll
        for (int m = 0; m < 4; ++m)
            af[m] = *reinterpret_cast<const bf16x8*>(&As[(wr * 64 + m * 16 + l15) * 32 + lg * 8]);
#pragma unroll
        for (int n = 0; n < 4; ++n)
            bfr[n] = *reinterpret_cast<const bf16x8*>(&Bs[(wc * 64 + n * 16 + l15) * 32 + lg * 8]);
#pragma unroll
        for (int m = 0; m < 4; ++m)
#pragma unroll
            for (int n = 0; n < 4; ++n)
                acc[m][n] = __builtin_amdgcn_mfma_f32_16x16x32_bf16(af[m], bfr[n], acc[m][n], 0, 0, 0);
    }

#pragma unroll
    for (int m = 0; m < 4; ++m) {
#pragma unroll
        for (int n = 0; n < 4; ++n) {
#pragma unroll
            for (int j = 0; j < 4; ++j) {
                int row = bm * 128 + wr * 64 + m * 16 + lg * 4 + j;
                int col = bn * 128 + wc * 64 + n * 16 + l15;
                if (OUT_BF16)
                    Cb[(size_t)row * N + col] = __float2bfloat16(acc[m][n][j]);
                else
                    Cf[(size_t)row * N + col] = acc[m][n][j];
            }
        }
    }
}

// ---------------------------------------------------------------------------
// Flash attention (causal), swapped-QK^T, key-permuted V, MAX-FREE softmax,
// MFMA ROW-SUM, triangle-paired 2-pass blocks, K AND V STAGED IN LDS.
// Grid (bh=64, y=16); each 2-wave block runs qt = 31-y then qt = y (33
// tile-iterations per block, perfectly balanced).
// Both waves of a block share one staged K-tile AND one staged V-tile per
// iteration (V was previously fetched per-wave from L2 — 3x the traffic).
// V tile of the key-permuted Vt has the same 64x128B shape as the K tile,
// so the same swizzled global_load_lds staging + conflict-free ds_read
// pattern applies; V is prefetched one full tile ahead.
// ---------------------------------------------------------------------------
__global__ __launch_bounds__(128) void attn_k(const __hip_bfloat16* __restrict__ qkv,
                                              const __hip_bfloat16* __restrict__ Vt,
                                              __hip_bfloat16* __restrict__ y) {
    constexpr int TT = 2048;
    constexpr int S3C = 3072;
    const int bh = blockIdx.x, b = bh >> 4, h = bh & 15;
    const int tid = threadIdx.x;
    const int wid = tid >> 6, lane = tid & 63;
    const int l15 = lane & 15, lg = lane >> 4;

    __shared__ __attribute__((aligned(16))) char Ks[2][64 * 128];  // [key][d-chunk^swz]
    __shared__ __attribute__((aligned(16))) char Vs[2][64 * 128];  // [d][key-chunk^swz]

    const __hip_bfloat16* base = qkv + (size_t)b * TT * S3C;
    const int qo = h * 64, ko = 1024 + h * 64;
    const __hip_bfloat16* vt = Vt + (size_t)bh * 64 * TT;

    // B-fragment of ones for the MFMA row-sum
    bf16x8 vones;
#pragma unroll
    for (int i = 0; i < 8; ++i) vones[i] = tobf(1.0f);

    // stage one 64-key tile of K and of V (4+4 x 16B per thread, swizzled src)
#define STAGE(BUF, KT)                                                                             \
    do {                                                                                           \
        const int kb_ = (KT) * 64;                                                                 \
        _Pragma("unroll") for (int p_ = 0; p_ < 4; ++p_) {                                         \
            int idx_ = p_ * 128 + tid;                                                             \
            int row_ = idx_ >> 3, c_ = idx_ & 7;                                                   \
            int col_ = 8 * (c_ ^ (row_ & 7));                                                      \
            __builtin_amdgcn_global_load_lds(                                                      \
                (const __attribute__((address_space(1))) void*)(base + (size_t)(kb_ + row_) * S3C + ko + col_), \
                (__attribute__((address_space(3))) void*)(&Ks[BUF][idx_ * 16]), 16, 0, 0);         \
            __builtin_amdgcn_global_load_lds(                                                      \
                (const __attribute__((address_space(1))) void*)(vt + (size_t)row_ * TT + kb_ + col_), \
                (__attribute__((address_space(3))) void*)(&Vs[BUF][idx_ * 16]), 16, 0, 0);         \
        }                                                                                          \
    } while (0)

#pragma unroll 1
    for (int pass = 0; pass < 2; ++pass) {
        const int qt = pass == 0 ? (31 - (int)blockIdx.y) : (int)blockIdx.y;
        const int qbase = qt * 64 + wid * 32;
        const int nt = qt + 1;

        // Q B-fragments (pre-scaled by log2e/sqrt(C)): [m][half]
        bf16x8 aq[2][2];
#pragma unroll
        for (int m = 0; m < 2; ++m) {
            const __hip_bfloat16* qp = base + (size_t)(qbase + m * 16 + l15) * S3C + qo + lg * 8;
            aq[m][0] = *reinterpret_cast<const bf16x8*>(qp);
            aq[m][1] = *reinterpret_cast<const bf16x8*>(qp + 32);
        }

        f32x4 acc[2][4] = {};  // [m][dg]: row=q(lg*4+j), col=d(dg*16+l15)
        f32x4 lsum[2] = {};    // MFMA row-sums, same row layout as acc

        STAGE(0, 0);
        asm volatile("s_waitcnt vmcnt(0)" ::: "memory");
        __syncthreads();

        int cur = 0;
        for (int kt = 0; kt < nt; ++kt) {
            if (kt + 1 < nt) STAGE(cur ^ 1, kt + 1);
            const int kb = kt * 64;
            const char* Kb = &Ks[cur][0];
            const char* Vb = &Vs[cur][0];
            const int sw = l15 & 7;
            // ---- QK^T (swapped): s[m][cg][j] = S[key=kb+16cg+4lg+j][q=qbase+16m+l15]
            f32x4 s[2][4];
            __builtin_amdgcn_s_setprio(1);
#pragma unroll
            for (int cg = 0; cg < 4; ++cg) {
                const char* krow = Kb + (cg * 16 + l15) * 128;
                bf16x8 k0 = *reinterpret_cast<const bf16x8*>(krow + 16 * (lg ^ sw));
                bf16x8 k1 = *reinterpret_cast<const bf16x8*>(krow + 16 * ((4 + lg) ^ sw));
#pragma unroll
                for (int m = 0; m < 2; ++m) {
                    f32x4 z = {0.f, 0.f, 0.f, 0.f};
                    z = __builtin_amdgcn_mfma_f32_16x16x32_bf16(k0, aq[m][0], z, 0, 0, 0);
                    z = __builtin_amdgcn_mfma_f32_16x16x32_bf16(k1, aq[m][1], z, 0, 0, 0);
                    s[m][cg] = z;
                }
            }
            __builtin_amdgcn_s_setprio(0);
            // ---- V B-frags from shared LDS (same conflict-free pattern as K)
            bf16x8 vb[2][4];
#pragma unroll
            for (int dg = 0; dg < 4; ++dg) {
                const char* vrow = Vb + (dg * 16 + l15) * 128;
                vb[0][dg] = *reinterpret_cast<const bf16x8*>(vrow + 16 * (lg ^ sw));
                vb[1][dg] = *reinterpret_cast<const bf16x8*>(vrow + 16 * ((4 + lg) ^ sw));
            }
            // ---- max-free softmax: p = 2^s (masked -> 0); no row-sum VALU
            float p[2][4][4];
            const bool needmask = (kb + 63 > qbase);
#pragma unroll
            for (int m = 0; m < 2; ++m)
#pragma unroll
                for (int cg = 0; cg < 4; ++cg)
#pragma unroll
                    for (int j = 0; j < 4; ++j) {
                        float e = fexp2(s[m][cg][j]);
                        if (needmask) {
                            int key = kb + cg * 16 + lg * 4 + j;
                            int qrow = qbase + m * 16 + l15;
                            e = (key > qrow) ? 0.f : e;
                        }
                        p[m][cg][j] = e;
                    }
            // ---- P A-frags: pure register pack (key-permutation baked into Vt)
            bf16x8 pa[2][2];
#pragma unroll
            for (int m = 0; m < 2; ++m)
#pragma unroll
                for (int ks = 0; ks < 2; ++ks) {
                    bf16x8 t;
                    t[0] = tobf(p[m][2 * ks][0]);
                    t[1] = tobf(p[m][2 * ks][1]);
                    t[2] = tobf(p[m][2 * ks][2]);
                    t[3] = tobf(p[m][2 * ks][3]);
                    t[4] = tobf(p[m][2 * ks + 1][0]);
                    t[5] = tobf(p[m][2 * ks + 1][1]);
                    t[6] = tobf(p[m][2 * ks + 1][2]);
                    t[7] = tobf(p[m][2 * ks + 1][3]);
                    pa[m][ks] = t;
                }
            // ---- PV + MFMA row-sum
            __builtin_amdgcn_s_setprio(1);
#pragma unroll
            for (int ks = 0; ks < 2; ++ks) {
#pragma unroll
                for (int dg = 0; dg < 4; ++dg)
#pragma unroll
                    for (int m = 0; m < 2; ++m)
                        acc[m][dg] = __builtin_amdgcn_mfma_f32_16x16x32_bf16(pa[m][ks], vb[ks][dg],
                                                                             acc[m][dg], 0, 0, 0);
#pragma unroll
                for (int m = 0; m < 2; ++m)
                    lsum[m] = __builtin_amdgcn_mfma_f32_16x16x32_bf16(pa[m][ks], vones,
                                                                      lsum[m], 0, 0, 0);
            }
            __builtin_amdgcn_s_setprio(0);
            asm volatile("s_waitcnt vmcnt(0)" ::: "memory");
            __syncthreads();
            cur ^= 1;
        }

        // ---- epilogue: lsum already in acc row layout -> no cross-lane ops
#pragma unroll
        for (int m = 0; m < 2; ++m)
#pragma unroll
            for (int j = 0; j < 4; ++j) {
                float inv = 1.f / lsum[m][j];
                int t = qbase + m * 16 + lg * 4 + j;
#pragma unroll
                for (int dg = 0; dg < 4; ++dg) {
                    float o = acc[m][dg][j] * inv;
                    y[((size_t)(b * TT + t)) * 1024 + h * 64 + dg * 16 + l15] = __float2bfloat16(o);
                }
            }
    }
#undef STAGE
}

// ---------------------------------------------------------------------------
extern "C" void kernel_launch(void* const* d_in, const int* in_sizes, int n_in,
                              void* d_out, int out_size, void* d_ws, size_t ws_size,
                              hipStream_t stream) {
    const float* x = (const float*)d_in[0];   // [4,2048,1024]
    const float* Wa = (const float*)d_in[1];  // [1024,3072]
    const float* Wp = (const float*)d_in[2];  // [1024,1024]
    float* out = (float*)d_out;               // [4,2048,1024] fp32

    __hip_bfloat16* ws = (__hip_bfloat16*)d_ws;
    __hip_bfloat16* x_bf = ws;                          // 8192*1024 (dead after GEMM1)
    __hip_bfloat16* WaT = x_bf + (size_t)8192 * 1024;   // 3072*1024 (W_attn^T)
    __hip_bfloat16* WpT = WaT + (size_t)3072 * 1024;    // 1024*1024 (W_proj^T)
    __hip_bfloat16* qkv = WpT + (size_t)1024 * 1024;    // 8192*3072
    __hip_bfloat16* ybf = qkv + (size_t)8192 * 3072;    // 8192*1024
    __hip_bfloat16* Vt = x_bf;                          // reuse: 64*64*2048 = 8192*1024

    // fused prep: x cvt + W_attn^T (Q cols scaled by log2e/sqrt(C)) + W_proj^T
    prep_k<<<8192 + 3072 + 1024, 256, 0, stream>>>(x, x_bf, Wa, WaT, Wp, WpT);
    // qkv = x @ W_attn   (M=8192, N=3072, K=1024)
    gemm_bt<true><<<dim3(24, 64), 256, 0, stream>>>(x_bf, WaT, qkv, nullptr, 8192, 3072, 1024);
    // V^T per head, key-permuted (x_bf is dead now; Vt aliases it)
    vtrans_k<<<dim3(64, 2, 64), 256, 0, stream>>>(qkv, Vt);
    // flash attention -> ybf (triangle-paired 2-pass blocks, K+V LDS-staged)
    attn_k<<<dim3(64, 16), 128, 0, stream>>>(qkv, Vt, ybf);
    // out = y @ W_proj   (M=8192, N=1024, K=1024), fp32 out
    gemm_bt<false><<<dim3(8, 64), 256, 0, stream>>>(ybf, WpT, nullptr, out, 8192, 1024, 1024);
}

// Round 16
// 173.141 us; speedup vs baseline: 1.5887x; 1.0606x over previous
//
#include <hip/hip_runtime.h>
#include <hip/hip_bf16.h>

typedef __bf16 bf16x8 __attribute__((ext_vector_type(8)));
typedef float f32x4 __attribute__((ext_vector_type(4)));

static __device__ __forceinline__ __bf16 tobf(float x) {
    __hip_bfloat16 h = __float2bfloat16(x);
    __bf16 r;
    __builtin_memcpy(&r, &h, 2);
    return r;
}

// fast 2^x: single v_exp_f32 (no libm range-fixup code)
static __device__ __forceinline__ float fexp2(float x) {
    float r;
    asm("v_exp_f32 %0, %1" : "=v"(r) : "v"(x));
    return r;
}

// ---------------------------------------------------------------------------
// Fused prep: (a) x fp32 -> bf16 (vectorized), (b) W_attn^T with qscale
// folded into Q columns, (c) W_proj^T.  One launch instead of three.
// ---------------------------------------------------------------------------
__global__ __launch_bounds__(256) void prep_k(const float* __restrict__ x,
                                              __hip_bfloat16* __restrict__ x_bf,
                                              const float* __restrict__ Wa,
                                              __hip_bfloat16* __restrict__ WaT,
                                              const float* __restrict__ Wp,
                                              __hip_bfloat16* __restrict__ WpT) {
    __shared__ float tile[32][33];
    const int bid = blockIdx.x;
    const int tid = threadIdx.x;
    if (bid < 8192) {
        int i = bid * 256 + tid;
        float4 v = reinterpret_cast<const float4*>(x)[i];
        __hip_bfloat16 a = __float2bfloat16(v.x);
        __hip_bfloat16 b = __float2bfloat16(v.y);
        __hip_bfloat16 c = __float2bfloat16(v.z);
        __hip_bfloat16 d = __float2bfloat16(v.w);
        ushort4 o;
        o.x = *reinterpret_cast<unsigned short*>(&a);
        o.y = *reinterpret_cast<unsigned short*>(&b);
        o.z = *reinterpret_cast<unsigned short*>(&c);
        o.w = *reinterpret_cast<unsigned short*>(&d);
        reinterpret_cast<ushort4*>(x_bf)[i] = o;
        return;
    }
    const float* in;
    __hip_bfloat16* out;
    int bx, Cn, qrows;
    float qscale;
    int t;
    if (bid < 8192 + 3072) {
        t = bid - 8192;
        in = Wa; out = WaT; Cn = 3072; qrows = 1024;
        qscale = 0.045084223f;  // log2(e)/sqrt(1024)
        bx = t % 96;
    } else {
        t = bid - 11264;
        in = Wp; out = WpT; Cn = 1024; qrows = 0;
        qscale = 1.0f;
        bx = t % 32;
    }
    const int by = (bid < 11264) ? (t / 96) : (t / 32);
    const int R = 1024;
    const int c0 = bx * 32, r0 = by * 32;
    const int tx = tid & 31, ty = tid >> 5;  // 32 x 8
#pragma unroll
    for (int i = 0; i < 4; ++i)
        tile[ty + i * 8][tx] = in[(size_t)(r0 + ty + i * 8) * Cn + c0 + tx];
    __syncthreads();
#pragma unroll
    for (int i = 0; i < 4; ++i) {
        int orow = c0 + ty + i * 8;
        float v = tile[tx][ty + i * 8];
        if (orow < qrows) v *= qscale;
        out[(size_t)orow * R + r0 + tx] = __float2bfloat16(v);
    }
}

// ---------------------------------------------------------------------------
// V transpose + key-permute: qkv V-section [b][t][h*64+d] ->
// Vt[(b*16+h)*64+d][slot(t)], slot(r) = ((r&12)<<1)|(r&3)|((r>>4)<<2) within
// each 32-key block. Matches the register layout of swapped-QK^T P frags so
// the PV A-operand is a pure register pack.
// ---------------------------------------------------------------------------
__global__ __launch_bounds__(256) void vtrans_k(const __hip_bfloat16* __restrict__ qkv,
                                                __hip_bfloat16* __restrict__ Vt) {
    __shared__ __hip_bfloat16 tile[32][33];
    const int bh = blockIdx.z, b = bh >> 4, h = bh & 15;
    const int tt = blockIdx.x;  // 0..63 (t tile)
    const int dt = blockIdx.y;  // 0..1  (d tile)
    const int tx = threadIdx.x & 31, ty = threadIdx.x >> 5;  // 32 x 8
    const __hip_bfloat16* src = qkv + (size_t)b * 2048 * 3072 + 2048 + h * 64;
#pragma unroll
    for (int i = 0; i < 4; ++i)
        tile[ty + i * 8][tx] = src[(size_t)(tt * 32 + ty + i * 8) * 3072 + dt * 32 + tx];
    __syncthreads();
    const int slot = ((tx & 12) << 1) | (tx & 3) | ((tx >> 4) << 2);
    __hip_bfloat16* dst = Vt + ((size_t)bh * 64 + dt * 32) * 2048 + tt * 32;
#pragma unroll
    for (int i = 0; i < 4; ++i)
        dst[(size_t)(ty + i * 8) * 2048 + slot] = tile[tx][ty + i * 8];
}

// ---------------------------------------------------------------------------
// bf16 GEMM, C = A[M][K] * B, with B given transposed: Bt[N][K].
// 128x128 tile, BK=64, 4 waves each owning 64x64. LDS rows are 128 B with
// chunk-XOR swizzle (c ^= row&7): pre-swizzled global source + linear
// global_load_lds dest + swizzled ds_read_b128 -> ZERO bank conflicts
// (same pattern as attn_k's K/V staging, measured conflict-free).
// Halves barrier count vs BK=32. XCD-aware tile swizzle.
// ---------------------------------------------------------------------------
template <bool OUT_BF16>
__global__ __launch_bounds__(256) void gemm_bt(const __hip_bfloat16* __restrict__ A,
                                               const __hip_bfloat16* __restrict__ Bt,
                                               __hip_bfloat16* __restrict__ Cb,
                                               float* __restrict__ Cf,
                                               int M, int N, int K) {
    __shared__ __attribute__((aligned(16))) char As[128 * 128];  // bf16 [128 rows][64 k]
    __shared__ __attribute__((aligned(16))) char Bs[128 * 128];
    const int tid = threadIdx.x;
    const int lane = tid & 63, wid = tid >> 6;
    const int l15 = lane & 15, lg = lane >> 4;
    const int wr = wid >> 1, wc = wid & 1;
    const int lin = blockIdx.y * gridDim.x + blockIdx.x;
    const int cpx = (gridDim.x * gridDim.y) >> 3;
    const int sw = (lin & 7) * cpx + (lin >> 3);
    const int bn = sw % gridDim.x, bm = sw / gridDim.x;
    const size_t arow0 = (size_t)bm * 128;
    const size_t brow0 = (size_t)bn * 128;

    f32x4 acc[4][4] = {};

    const int nk = K >> 6;
    for (int kt = 0; kt < nk; ++kt) {
        __syncthreads();
        {
            const int k0 = kt * 64;
#pragma unroll
            for (int p = 0; p < 4; ++p) {
                int idx = p * 256 + tid;
                int row = idx >> 3;
                int c = idx & 7;
                int col = 8 * (c ^ (row & 7));  // pre-swizzled source chunk
                const __hip_bfloat16* ga = A + (arow0 + row) * (size_t)K + k0 + col;
                const __hip_bfloat16* gb = Bt + (brow0 + row) * (size_t)K + k0 + col;
                __builtin_amdgcn_global_load_lds(
                    (const __attribute__((address_space(1))) void*)ga,
                    (__attribute__((address_space(3))) void*)(&As[idx * 16]), 16, 0, 0);
                __builtin_amdgcn_global_load_lds(
                    (const __attribute__((address_space(1))) void*)gb,
                    (__attribute__((address_space(3))) void*)(&Bs[idx * 16]), 16, 0, 0);
            }
        }
        __syncthreads();
        const int swz = l15 & 7;
#pragma unroll
        for (int ks = 0; ks < 2; ++ks) {
            bf16x8 af[4], bfr[4];
#pragma unroll
            for (int m = 0; m < 4; ++m)
                af[m] = *reinterpret_cast<const bf16x8*>(
                    &As[(wr * 64 + m * 16 + l15) * 128 + 16 * ((ks * 4 + lg) ^ swz)]);
#pragma unroll
            for (int n = 0; n < 4; ++n)
                bfr[n] = *reinterpret_cast<const bf16x8*>(
                    &Bs[(wc * 64 + n * 16 + l15) * 128 + 16 * ((ks * 4 + lg) ^ swz)]);
#pragma unroll
            for (int m = 0; m < 4; ++m)
#pragma unroll
                for (int n = 0; n < 4; ++n)
                    acc[m][n] = __builtin_amdgcn_mfma_f32_16x16x32_bf16(af[m], bfr[n], acc[m][n], 0, 0, 0);
        }
    }

#pragma unroll
    for (int m = 0; m < 4; ++m) {
#pragma unroll
        for (int n = 0; n < 4; ++n) {
#pragma unroll
            for (int j = 0; j < 4; ++j) {
                int row = bm * 128 + wr * 64 + m * 16 + lg * 4 + j;
                int col = bn * 128 + wc * 64 + n * 16 + l15;
                if (OUT_BF16)
                    Cb[(size_t)row * N + col] = __float2bfloat16(acc[m][n][j]);
                else
                    Cf[(size_t)row * N + col] = acc[m][n][j];
            }
        }
    }
}

// ---------------------------------------------------------------------------
// Flash attention (causal), swapped-QK^T, key-permuted V, MAX-FREE softmax,
// MFMA ROW-SUM, triangle-paired 2-pass blocks, K AND V STAGED IN LDS.
// (unchanged from round 15)
// ---------------------------------------------------------------------------
__global__ __launch_bounds__(128) void attn_k(const __hip_bfloat16* __restrict__ qkv,
                                              const __hip_bfloat16* __restrict__ Vt,
                                              __hip_bfloat16* __restrict__ y) {
    constexpr int TT = 2048;
    constexpr int S3C = 3072;
    const int bh = blockIdx.x, b = bh >> 4, h = bh & 15;
    const int tid = threadIdx.x;
    const int wid = tid >> 6, lane = tid & 63;
    const int l15 = lane & 15, lg = lane >> 4;

    __shared__ __attribute__((aligned(16))) char Ks[2][64 * 128];  // [key][d-chunk^swz]
    __shared__ __attribute__((aligned(16))) char Vs[2][64 * 128];  // [d][key-chunk^swz]

    const __hip_bfloat16* base = qkv + (size_t)b * TT * S3C;
    const int qo = h * 64, ko = 1024 + h * 64;
    const __hip_bfloat16* vt = Vt + (size_t)bh * 64 * TT;

    // B-fragment of ones for the MFMA row-sum
    bf16x8 vones;
#pragma unroll
    for (int i = 0; i < 8; ++i) vones[i] = tobf(1.0f);

    // stage one 64-key tile of K and of V (4+4 x 16B per thread, swizzled src)
#define STAGE(BUF, KT)                                                                             \
    do {                                                                                           \
        const int kb_ = (KT) * 64;                                                                 \
        _Pragma("unroll") for (int p_ = 0; p_ < 4; ++p_) {                                         \
            int idx_ = p_ * 128 + tid;                                                             \
            int row_ = idx_ >> 3, c_ = idx_ & 7;                                                   \
            int col_ = 8 * (c_ ^ (row_ & 7));                                                      \
            __builtin_amdgcn_global_load_lds(                                                      \
                (const __attribute__((address_space(1))) void*)(base + (size_t)(kb_ + row_) * S3C + ko + col_), \
                (__attribute__((address_space(3))) void*)(&Ks[BUF][idx_ * 16]), 16, 0, 0);         \
            __builtin_amdgcn_global_load_lds(                                                      \
                (const __attribute__((address_space(1))) void*)(vt + (size_t)row_ * TT + kb_ + col_), \
                (__attribute__((address_space(3))) void*)(&Vs[BUF][idx_ * 16]), 16, 0, 0);         \
        }                                                                                          \
    } while (0)

#pragma unroll 1
    for (int pass = 0; pass < 2; ++pass) {
        const int qt = pass == 0 ? (31 - (int)blockIdx.y) : (int)blockIdx.y;
        const int qbase = qt * 64 + wid * 32;
        const int nt = qt + 1;

        // Q B-fragments (pre-scaled by log2e/sqrt(C)): [m][half]
        bf16x8 aq[2][2];
#pragma unroll
        for (int m = 0; m < 2; ++m) {
            const __hip_bfloat16* qp = base + (size_t)(qbase + m * 16 + l15) * S3C + qo + lg * 8;
            aq[m][0] = *reinterpret_cast<const bf16x8*>(qp);
            aq[m][1] = *reinterpret_cast<const bf16x8*>(qp + 32);
        }

        f32x4 acc[2][4] = {};  // [m][dg]: row=q(lg*4+j), col=d(dg*16+l15)
        f32x4 lsum[2] = {};    // MFMA row-sums, same row layout as acc

        STAGE(0, 0);
        asm volatile("s_waitcnt vmcnt(0)" ::: "memory");
        __syncthreads();

        int cur = 0;
        for (int kt = 0; kt < nt; ++kt) {
            if (kt + 1 < nt) STAGE(cur ^ 1, kt + 1);
            const int kb = kt * 64;
            const char* Kb = &Ks[cur][0];
            const char* Vb = &Vs[cur][0];
            const int sw = l15 & 7;
            // ---- QK^T (swapped): s[m][cg][j] = S[key=kb+16cg+4lg+j][q=qbase+16m+l15]
            f32x4 s[2][4];
            __builtin_amdgcn_s_setprio(1);
#pragma unroll
            for (int cg = 0; cg < 4; ++cg) {
                const char* krow = Kb + (cg * 16 + l15) * 128;
                bf16x8 k0 = *reinterpret_cast<const bf16x8*>(krow + 16 * (lg ^ sw));
                bf16x8 k1 = *reinterpret_cast<const bf16x8*>(krow + 16 * ((4 + lg) ^ sw));
#pragma unroll
                for (int m = 0; m < 2; ++m) {
                    f32x4 z = {0.f, 0.f, 0.f, 0.f};
                    z = __builtin_amdgcn_mfma_f32_16x16x32_bf16(k0, aq[m][0], z, 0, 0, 0);
                    z = __builtin_amdgcn_mfma_f32_16x16x32_bf16(k1, aq[m][1], z, 0, 0, 0);
                    s[m][cg] = z;
                }
            }
            __builtin_amdgcn_s_setprio(0);
            // ---- V B-frags from shared LDS (same conflict-free pattern as K)
            bf16x8 vb[2][4];
#pragma unroll
            for (int dg = 0; dg < 4; ++dg) {
                const char* vrow = Vb + (dg * 16 + l15) * 128;
                vb[0][dg] = *reinterpret_cast<const bf16x8*>(vrow + 16 * (lg ^ sw));
                vb[1][dg] = *reinterpret_cast<const bf16x8*>(vrow + 16 * ((4 + lg) ^ sw));
            }
            // ---- max-free softmax: p = 2^s (masked -> 0); no row-sum VALU
            float p[2][4][4];
            const bool needmask = (kb + 63 > qbase);
#pragma unroll
            for (int m = 0; m < 2; ++m)
#pragma unroll
                for (int cg = 0; cg < 4; ++cg)
#pragma unroll
                    for (int j = 0; j < 4; ++j) {
                        float e = fexp2(s[m][cg][j]);
                        if (needmask) {
                            int key = kb + cg * 16 + lg * 4 + j;
                            int qrow = qbase + m * 16 + l15;
                            e = (key > qrow) ? 0.f : e;
                        }
                        p[m][cg][j] = e;
                    }
            // ---- P A-frags: pure register pack (key-permutation baked into Vt)
            bf16x8 pa[2][2];
#pragma unroll
            for (int m = 0; m < 2; ++m)
#pragma unroll
                for (int ks = 0; ks < 2; ++ks) {
                    bf16x8 t;
                    t[0] = tobf(p[m][2 * ks][0]);
                    t[1] = tobf(p[m][2 * ks][1]);
                    t[2] = tobf(p[m][2 * ks][2]);
                    t[3] = tobf(p[m][2 * ks][3]);
                    t[4] = tobf(p[m][2 * ks + 1][0]);
                    t[5] = tobf(p[m][2 * ks + 1][1]);
                    t[6] = tobf(p[m][2 * ks + 1][2]);
                    t[7] = tobf(p[m][2 * ks + 1][3]);
                    pa[m][ks] = t;
                }
            // ---- PV + MFMA row-sum
            __builtin_amdgcn_s_setprio(1);
#pragma unroll
            for (int ks = 0; ks < 2; ++ks) {
#pragma unroll
                for (int dg = 0; dg < 4; ++dg)
#pragma unroll
                    for (int m = 0; m < 2; ++m)
                        acc[m][dg] = __builtin_amdgcn_mfma_f32_16x16x32_bf16(pa[m][ks], vb[ks][dg],
                                                                             acc[m][dg], 0, 0, 0);
#pragma unroll
                for (int m = 0; m < 2; ++m)
                    lsum[m] = __builtin_amdgcn_mfma_f32_16x16x32_bf16(pa[m][ks], vones,
                                                                      lsum[m], 0, 0, 0);
            }
            __builtin_amdgcn_s_setprio(0);
            asm volatile("s_waitcnt vmcnt(0)" ::: "memory");
            __syncthreads();
            cur ^= 1;
        }

        // ---- epilogue: lsum already in acc row layout -> no cross-lane ops
#pragma unroll
        for (int m = 0; m < 2; ++m)
#pragma unroll
            for (int j = 0; j < 4; ++j) {
                float inv = 1.f / lsum[m][j];
                int t = qbase + m * 16 + lg * 4 + j;
#pragma unroll
                for (int dg = 0; dg < 4; ++dg) {
                    float o = acc[m][dg][j] * inv;
                    y[((size_t)(b * TT + t)) * 1024 + h * 64 + dg * 16 + l15] = __float2bfloat16(o);
                }
            }
    }
#undef STAGE
}

// ---------------------------------------------------------------------------
extern "C" void kernel_launch(void* const* d_in, const int* in_sizes, int n_in,
                              void* d_out, int out_size, void* d_ws, size_t ws_size,
                              hipStream_t stream) {
    const float* x = (const float*)d_in[0];   // [4,2048,1024]
    const float* Wa = (const float*)d_in[1];  // [1024,3072]
    const float* Wp = (const float*)d_in[2];  // [1024,1024]
    float* out = (float*)d_out;               // [4,2048,1024] fp32

    __hip_bfloat16* ws = (__hip_bfloat16*)d_ws;
    __hip_bfloat16* x_bf = ws;                          // 8192*1024 (dead after GEMM1)
    __hip_bfloat16* WaT = x_bf + (size_t)8192 * 1024;   // 3072*1024 (W_attn^T)
    __hip_bfloat16* WpT = WaT + (size_t)3072 * 1024;    // 1024*1024 (W_proj^T)
    __hip_bfloat16* qkv = WpT + (size_t)1024 * 1024;    // 8192*3072
    __hip_bfloat16* ybf = qkv + (size_t)8192 * 3072;    // 8192*1024
    __hip_bfloat16* Vt = x_bf;                          // reuse: 64*64*2048 = 8192*1024

    // fused prep: x cvt + W_attn^T (Q cols scaled by log2e/sqrt(C)) + W_proj^T
    prep_k<<<8192 + 3072 + 1024, 256, 0, stream>>>(x, x_bf, Wa, WaT, Wp, WpT);
    // qkv = x @ W_attn   (M=8192, N=3072, K=1024)
    gemm_bt<true><<<dim3(24, 64), 256, 0, stream>>>(x_bf, WaT, qkv, nullptr, 8192, 3072, 1024);
    // V^T per head, key-permuted (x_bf is dead now; Vt aliases it)
    vtrans_k<<<dim3(64, 2, 64), 256, 0, stream>>>(qkv, Vt);
    // flash attention -> ybf (triangle-paired 2-pass blocks, K+V LDS-staged)
    attn_k<<<dim3(64, 16), 128, 0, stream>>>(qkv, Vt, ybf);
    // out = y @ W_proj   (M=8192, N=1024, K=1024), fp32 out
    gemm_bt<false><<<dim3(8, 64), 256, 0, stream>>>(ybf, WpT, nullptr, out, 8192, 1024, 1024);
}

// Round 17
// 171.285 us; speedup vs baseline: 1.6060x; 1.0108x over previous
//
#include <hip/hip_runtime.h>
#include <hip/hip_bf16.h>

typedef __bf16 bf16x8 __attribute__((ext_vector_type(8)));
typedef float f32x4 __attribute__((ext_vector_type(4)));

static __device__ __forceinline__ __bf16 tobf(float x) {
    __hip_bfloat16 h = __float2bfloat16(x);
    __bf16 r;
    __builtin_memcpy(&r, &h, 2);
    return r;
}

// fast 2^x: single v_exp_f32 (no libm range-fixup code)
static __device__ __forceinline__ float fexp2(float x) {
    float r;
    asm("v_exp_f32 %0, %1" : "=v"(r) : "v"(x));
    return r;
}

// ---------------------------------------------------------------------------
// Fused prep: (a) x fp32 -> bf16 (vectorized), (b) W_attn^T with qscale
// folded into Q columns, (c) W_proj^T.  One launch instead of three.
// ---------------------------------------------------------------------------
__global__ __launch_bounds__(256) void prep_k(const float* __restrict__ x,
                                              __hip_bfloat16* __restrict__ x_bf,
                                              const float* __restrict__ Wa,
                                              __hip_bfloat16* __restrict__ WaT,
                                              const float* __restrict__ Wp,
                                              __hip_bfloat16* __restrict__ WpT) {
    __shared__ float tile[32][33];
    const int bid = blockIdx.x;
    const int tid = threadIdx.x;
    if (bid < 8192) {
        int i = bid * 256 + tid;
        float4 v = reinterpret_cast<const float4*>(x)[i];
        __hip_bfloat16 a = __float2bfloat16(v.x);
        __hip_bfloat16 b = __float2bfloat16(v.y);
        __hip_bfloat16 c = __float2bfloat16(v.z);
        __hip_bfloat16 d = __float2bfloat16(v.w);
        ushort4 o;
        o.x = *reinterpret_cast<unsigned short*>(&a);
        o.y = *reinterpret_cast<unsigned short*>(&b);
        o.z = *reinterpret_cast<unsigned short*>(&c);
        o.w = *reinterpret_cast<unsigned short*>(&d);
        reinterpret_cast<ushort4*>(x_bf)[i] = o;
        return;
    }
    const float* in;
    __hip_bfloat16* out;
    int bx, Cn, qrows;
    float qscale;
    int t;
    if (bid < 8192 + 3072) {
        t = bid - 8192;
        in = Wa; out = WaT; Cn = 3072; qrows = 1024;
        qscale = 0.045084223f;  // log2(e)/sqrt(1024)
        bx = t % 96;
    } else {
        t = bid - 11264;
        in = Wp; out = WpT; Cn = 1024; qrows = 0;
        qscale = 1.0f;
        bx = t % 32;
    }
    const int by = (bid < 11264) ? (t / 96) : (t / 32);
    const int R = 1024;
    const int c0 = bx * 32, r0 = by * 32;
    const int tx = tid & 31, ty = tid >> 5;  // 32 x 8
#pragma unroll
    for (int i = 0; i < 4; ++i)
        tile[ty + i * 8][tx] = in[(size_t)(r0 + ty + i * 8) * Cn + c0 + tx];
    __syncthreads();
#pragma unroll
    for (int i = 0; i < 4; ++i) {
        int orow = c0 + ty + i * 8;
        float v = tile[tx][ty + i * 8];
        if (orow < qrows) v *= qscale;
        out[(size_t)orow * R + r0 + tx] = __float2bfloat16(v);
    }
}

// ---------------------------------------------------------------------------
// V transpose + key-permute: qkv V-section [b][t][h*64+d] ->
// Vt[(b*16+h)*64+d][slot(t)], slot(r) = ((r&12)<<1)|(r&3)|((r>>4)<<2) within
// each 32-key block. Matches the register layout of swapped-QK^T P frags so
// the PV A-operand is a pure register pack.
// ---------------------------------------------------------------------------
__global__ __launch_bounds__(256) void vtrans_k(const __hip_bfloat16* __restrict__ qkv,
                                                __hip_bfloat16* __restrict__ Vt) {
    __shared__ __hip_bfloat16 tile[32][33];
    const int bh = blockIdx.z, b = bh >> 4, h = bh & 15;
    const int tt = blockIdx.x;  // 0..63 (t tile)
    const int dt = blockIdx.y;  // 0..1  (d tile)
    const int tx = threadIdx.x & 31, ty = threadIdx.x >> 5;  // 32 x 8
    const __hip_bfloat16* src = qkv + (size_t)b * 2048 * 3072 + 2048 + h * 64;
#pragma unroll
    for (int i = 0; i < 4; ++i)
        tile[ty + i * 8][tx] = src[(size_t)(tt * 32 + ty + i * 8) * 3072 + dt * 32 + tx];
    __syncthreads();
    const int slot = ((tx & 12) << 1) | (tx & 3) | ((tx >> 4) << 2);
    __hip_bfloat16* dst = Vt + ((size_t)bh * 64 + dt * 32) * 2048 + tt * 32;
#pragma unroll
    for (int i = 0; i < 4; ++i)
        dst[(size_t)(ty + i * 8) * 2048 + slot] = tile[tx][ty + i * 8];
}

// ---------------------------------------------------------------------------
// bf16 GEMM, C = A[M][K] * B, with B given transposed: Bt[N][K].
// 128x128 tile, BK=64, chunk-XOR swizzle, zero bank conflicts. XCD swizzle.
// (unchanged from round 16)
// ---------------------------------------------------------------------------
template <bool OUT_BF16>
__global__ __launch_bounds__(256) void gemm_bt(const __hip_bfloat16* __restrict__ A,
                                               const __hip_bfloat16* __restrict__ Bt,
                                               __hip_bfloat16* __restrict__ Cb,
                                               float* __restrict__ Cf,
                                               int M, int N, int K) {
    __shared__ __attribute__((aligned(16))) char As[128 * 128];  // bf16 [128 rows][64 k]
    __shared__ __attribute__((aligned(16))) char Bs[128 * 128];
    const int tid = threadIdx.x;
    const int lane = tid & 63, wid = tid >> 6;
    const int l15 = lane & 15, lg = lane >> 4;
    const int wr = wid >> 1, wc = wid & 1;
    const int lin = blockIdx.y * gridDim.x + blockIdx.x;
    const int cpx = (gridDim.x * gridDim.y) >> 3;
    const int sw = (lin & 7) * cpx + (lin >> 3);
    const int bn = sw % gridDim.x, bm = sw / gridDim.x;
    const size_t arow0 = (size_t)bm * 128;
    const size_t brow0 = (size_t)bn * 128;

    f32x4 acc[4][4] = {};

    const int nk = K >> 6;
    for (int kt = 0; kt < nk; ++kt) {
        __syncthreads();
        {
            const int k0 = kt * 64;
#pragma unroll
            for (int p = 0; p < 4; ++p) {
                int idx = p * 256 + tid;
                int row = idx >> 3;
                int c = idx & 7;
                int col = 8 * (c ^ (row & 7));  // pre-swizzled source chunk
                const __hip_bfloat16* ga = A + (arow0 + row) * (size_t)K + k0 + col;
                const __hip_bfloat16* gb = Bt + (brow0 + row) * (size_t)K + k0 + col;
                __builtin_amdgcn_global_load_lds(
                    (const __attribute__((address_space(1))) void*)ga,
                    (__attribute__((address_space(3))) void*)(&As[idx * 16]), 16, 0, 0);
                __builtin_amdgcn_global_load_lds(
                    (const __attribute__((address_space(1))) void*)gb,
                    (__attribute__((address_space(3))) void*)(&Bs[idx * 16]), 16, 0, 0);
            }
        }
        __syncthreads();
        const int swz = l15 & 7;
#pragma unroll
        for (int ks = 0; ks < 2; ++ks) {
            bf16x8 af[4], bfr[4];
#pragma unroll
            for (int m = 0; m < 4; ++m)
                af[m] = *reinterpret_cast<const bf16x8*>(
                    &As[(wr * 64 + m * 16 + l15) * 128 + 16 * ((ks * 4 + lg) ^ swz)]);
#pragma unroll
            for (int n = 0; n < 4; ++n)
                bfr[n] = *reinterpret_cast<const bf16x8*>(
                    &Bs[(wc * 64 + n * 16 + l15) * 128 + 16 * ((ks * 4 + lg) ^ swz)]);
#pragma unroll
            for (int m = 0; m < 4; ++m)
#pragma unroll
                for (int n = 0; n < 4; ++n)
                    acc[m][n] = __builtin_amdgcn_mfma_f32_16x16x32_bf16(af[m], bfr[n], acc[m][n], 0, 0, 0);
        }
    }

#pragma unroll
    for (int m = 0; m < 4; ++m) {
#pragma unroll
        for (int n = 0; n < 4; ++n) {
#pragma unroll
            for (int j = 0; j < 4; ++j) {
                int row = bm * 128 + wr * 64 + m * 16 + lg * 4 + j;
                int col = bn * 128 + wc * 64 + n * 16 + l15;
                if (OUT_BF16)
                    Cb[(size_t)row * N + col] = __float2bfloat16(acc[m][n][j]);
                else
                    Cf[(size_t)row * N + col] = acc[m][n][j];
            }
        }
    }
}

// ---------------------------------------------------------------------------
// Flash attention (causal), swapped-QK^T, key-permuted V, MAX-FREE softmax,
// MFMA ROW-SUM, 4-WAVE BLOCKS (128 q-rows share one staged K/V tile),
// triangle-paired 2-pass blocks, hoisted staging pointers.
// Grid (bh=64, y=8); block runs super-tile st = 15-y then st = y; per pass
// blk_nt = 2*st+2 tiles -> 36 tile-iterations per block for every y.
// Each wave owns 32 q-rows (qbase = st*128 + wid*32); waves past their
// causal range skip compute but keep barriers (wave-uniform guard).
// Staging: 2 K + 2 V global_load_lds per thread per tile (half of the
// 2-wave version), with source pointers advanced by constant strides.
// ---------------------------------------------------------------------------
__global__ __launch_bounds__(256) void attn_k(const __hip_bfloat16* __restrict__ qkv,
                                              const __hip_bfloat16* __restrict__ Vt,
                                              __hip_bfloat16* __restrict__ y) {
    constexpr int TT = 2048;
    constexpr int S3C = 3072;
    const int bh = blockIdx.x, b = bh >> 4, h = bh & 15;
    const int tid = threadIdx.x;
    const int wid = tid >> 6, lane = tid & 63;
    const int l15 = lane & 15, lg = lane >> 4;

    __shared__ __attribute__((aligned(16))) char Ks[2][64 * 128];  // [key][d-chunk^swz]
    __shared__ __attribute__((aligned(16))) char Vs[2][64 * 128];  // [d][key-chunk^swz]

    const __hip_bfloat16* base = qkv + (size_t)b * TT * S3C;
    const int qo = h * 64, ko = 1024 + h * 64;
    const __hip_bfloat16* vt = Vt + (size_t)bh * 64 * TT;

    // B-fragment of ones for the MFMA row-sum
    bf16x8 vones;
#pragma unroll
    for (int i = 0; i < 8; ++i) vones[i] = tobf(1.0f);

    // staging unit geometry: 2 x 16B units per thread for K and V each
    const int idx0 = tid, idx1 = 256 + tid;
    const int r0 = idx0 >> 3, c0 = 8 * ((idx0 & 7) ^ (r0 & 7));
    const int r1 = idx1 >> 3, c1 = 8 * ((idx1 & 7) ^ (r1 & 7));

#pragma unroll 1
    for (int pass = 0; pass < 2; ++pass) {
        const int st = pass == 0 ? (15 - (int)blockIdx.y) : (int)blockIdx.y;
        const int qbase = st * 128 + wid * 32;
        const int my_nt = (qbase >> 6) + 1;  // tiles this wave computes
        const int blk_nt = st * 2 + 2;       // tiles the block stages

        // Q B-fragments (pre-scaled by log2e/sqrt(C)): [m][half]
        bf16x8 aq[2][2];
#pragma unroll
        for (int m = 0; m < 2; ++m) {
            const __hip_bfloat16* qp = base + (size_t)(qbase + m * 16 + l15) * S3C + qo + lg * 8;
            aq[m][0] = *reinterpret_cast<const bf16x8*>(qp);
            aq[m][1] = *reinterpret_cast<const bf16x8*>(qp + 32);
        }

        f32x4 acc[2][4] = {};  // [m][dg]: row=q(lg*4+j), col=d(dg*16+l15)
        f32x4 lsum[2] = {};    // MFMA row-sums, same row layout as acc

        // hoisted staging source pointers (advance by constant stride/tile)
        const __hip_bfloat16* kp0 = base + (size_t)r0 * S3C + ko + c0;
        const __hip_bfloat16* kp1 = base + (size_t)r1 * S3C + ko + c1;
        const __hip_bfloat16* vp0 = vt + (size_t)r0 * TT + c0;
        const __hip_bfloat16* vp1 = vt + (size_t)r1 * TT + c1;

        auto stage = [&](int buf) {
            char* Kd = buf ? &Ks[1][0] : &Ks[0][0];
            char* Vd = buf ? &Vs[1][0] : &Vs[0][0];
            __builtin_amdgcn_global_load_lds(
                (const __attribute__((address_space(1))) void*)kp0,
                (__attribute__((address_space(3))) void*)(Kd + idx0 * 16), 16, 0, 0);
            __builtin_amdgcn_global_load_lds(
                (const __attribute__((address_space(1))) void*)kp1,
                (__attribute__((address_space(3))) void*)(Kd + idx1 * 16), 16, 0, 0);
            __builtin_amdgcn_global_load_lds(
                (const __attribute__((address_space(1))) void*)vp0,
                (__attribute__((address_space(3))) void*)(Vd + idx0 * 16), 16, 0, 0);
            __builtin_amdgcn_global_load_lds(
                (const __attribute__((address_space(1))) void*)vp1,
                (__attribute__((address_space(3))) void*)(Vd + idx1 * 16), 16, 0, 0);
            kp0 += (size_t)64 * S3C;
            kp1 += (size_t)64 * S3C;
            vp0 += 64;
            vp1 += 64;
        };

        stage(0);
        asm volatile("s_waitcnt vmcnt(0)" ::: "memory");
        __syncthreads();

        int cur = 0;
        for (int kt = 0; kt < blk_nt; ++kt) {
            if (kt + 1 < blk_nt) stage(cur ^ 1);
            if (kt < my_nt) {
                const int kb = kt * 64;
                const char* Kb = cur ? &Ks[1][0] : &Ks[0][0];
                const char* Vb = cur ? &Vs[1][0] : &Vs[0][0];
                const int swl = l15 & 7;
                // ---- QK^T (swapped): s[m][cg][j] = S[key=kb+16cg+4lg+j][q=qbase+16m+l15]
                f32x4 s[2][4];
                __builtin_amdgcn_s_setprio(1);
#pragma unroll
                for (int cg = 0; cg < 4; ++cg) {
                    const char* krow = Kb + (cg * 16 + l15) * 128;
                    bf16x8 k0 = *reinterpret_cast<const bf16x8*>(krow + 16 * (lg ^ swl));
                    bf16x8 k1 = *reinterpret_cast<const bf16x8*>(krow + 16 * ((4 + lg) ^ swl));
#pragma unroll
                    for (int m = 0; m < 2; ++m) {
                        f32x4 z = {0.f, 0.f, 0.f, 0.f};
                        z = __builtin_amdgcn_mfma_f32_16x16x32_bf16(k0, aq[m][0], z, 0, 0, 0);
                        z = __builtin_amdgcn_mfma_f32_16x16x32_bf16(k1, aq[m][1], z, 0, 0, 0);
                        s[m][cg] = z;
                    }
                }
                __builtin_amdgcn_s_setprio(0);
                // ---- V B-frags from shared LDS (conflict-free pattern)
                bf16x8 vb[2][4];
#pragma unroll
                for (int dg = 0; dg < 4; ++dg) {
                    const char* vrow = Vb + (dg * 16 + l15) * 128;
                    vb[0][dg] = *reinterpret_cast<const bf16x8*>(vrow + 16 * (lg ^ swl));
                    vb[1][dg] = *reinterpret_cast<const bf16x8*>(vrow + 16 * ((4 + lg) ^ swl));
                }
                // ---- max-free softmax: p = 2^s (masked -> 0)
                float p[2][4][4];
                const bool needmask = (kb + 63 > qbase);
#pragma unroll
                for (int m = 0; m < 2; ++m)
#pragma unroll
                    for (int cg = 0; cg < 4; ++cg)
#pragma unroll
                        for (int j = 0; j < 4; ++j) {
                            float e = fexp2(s[m][cg][j]);
                            if (needmask) {
                                int key = kb + cg * 16 + lg * 4 + j;
                                int qrow = qbase + m * 16 + l15;
                                e = (key > qrow) ? 0.f : e;
                            }
                            p[m][cg][j] = e;
                        }
                // ---- P A-frags: pure register pack (key-permute baked into Vt)
                bf16x8 pa[2][2];
#pragma unroll
                for (int m = 0; m < 2; ++m)
#pragma unroll
                    for (int ks = 0; ks < 2; ++ks) {
                        bf16x8 tt2;
                        tt2[0] = tobf(p[m][2 * ks][0]);
                        tt2[1] = tobf(p[m][2 * ks][1]);
                        tt2[2] = tobf(p[m][2 * ks][2]);
                        tt2[3] = tobf(p[m][2 * ks][3]);
                        tt2[4] = tobf(p[m][2 * ks + 1][0]);
                        tt2[5] = tobf(p[m][2 * ks + 1][1]);
                        tt2[6] = tobf(p[m][2 * ks + 1][2]);
                        tt2[7] = tobf(p[m][2 * ks + 1][3]);
                        pa[m][ks] = tt2;
                    }
                // ---- PV + MFMA row-sum
                __builtin_amdgcn_s_setprio(1);
#pragma unroll
                for (int ks = 0; ks < 2; ++ks) {
#pragma unroll
                    for (int dg = 0; dg < 4; ++dg)
#pragma unroll
                        for (int m = 0; m < 2; ++m)
                            acc[m][dg] = __builtin_amdgcn_mfma_f32_16x16x32_bf16(
                                pa[m][ks], vb[ks][dg], acc[m][dg], 0, 0, 0);
#pragma unroll
                    for (int m = 0; m < 2; ++m)
                        lsum[m] = __builtin_amdgcn_mfma_f32_16x16x32_bf16(pa[m][ks], vones,
                                                                          lsum[m], 0, 0, 0);
                }
                __builtin_amdgcn_s_setprio(0);
            }
            asm volatile("s_waitcnt vmcnt(0)" ::: "memory");
            __syncthreads();
            cur ^= 1;
        }

        // ---- epilogue: lsum already in acc row layout -> no cross-lane ops
#pragma unroll
        for (int m = 0; m < 2; ++m)
#pragma unroll
            for (int j = 0; j < 4; ++j) {
                float inv = 1.f / lsum[m][j];
                int t = qbase + m * 16 + lg * 4 + j;
#pragma unroll
                for (int dg = 0; dg < 4; ++dg) {
                    float o = acc[m][dg][j] * inv;
                    y[((size_t)(b * TT + t)) * 1024 + h * 64 + dg * 16 + l15] = __float2bfloat16(o);
                }
            }
    }
}

// ---------------------------------------------------------------------------
extern "C" void kernel_launch(void* const* d_in, const int* in_sizes, int n_in,
                              void* d_out, int out_size, void* d_ws, size_t ws_size,
                              hipStream_t stream) {
    const float* x = (const float*)d_in[0];   // [4,2048,1024]
    const float* Wa = (const float*)d_in[1];  // [1024,3072]
    const float* Wp = (const float*)d_in[2];  // [1024,1024]
    float* out = (float*)d_out;               // [4,2048,1024] fp32

    __hip_bfloat16* ws = (__hip_bfloat16*)d_ws;
    __hip_bfloat16* x_bf = ws;                          // 8192*1024 (dead after GEMM1)
    __hip_bfloat16* WaT = x_bf + (size_t)8192 * 1024;   // 3072*1024 (W_attn^T)
    __hip_bfloat16* WpT = WaT + (size_t)3072 * 1024;    // 1024*1024 (W_proj^T)
    __hip_bfloat16* qkv = WpT + (size_t)1024 * 1024;    // 8192*3072
    __hip_bfloat16* ybf = qkv + (size_t)8192 * 3072;    // 8192*1024
    __hip_bfloat16* Vt = x_bf;                          // reuse: 64*64*2048 = 8192*1024

    // fused prep: x cvt + W_attn^T (Q cols scaled by log2e/sqrt(C)) + W_proj^T
    prep_k<<<8192 + 3072 + 1024, 256, 0, stream>>>(x, x_bf, Wa, WaT, Wp, WpT);
    // qkv = x @ W_attn   (M=8192, N=3072, K=1024)
    gemm_bt<true><<<dim3(24, 64), 256, 0, stream>>>(x_bf, WaT, qkv, nullptr, 8192, 3072, 1024);
    // V^T per head, key-permuted (x_bf is dead now; Vt aliases it)
    vtrans_k<<<dim3(64, 2, 64), 256, 0, stream>>>(qkv, Vt);
    // flash attention -> ybf (4-wave triangle-paired blocks, 64x8 grid)
    attn_k<<<dim3(64, 8), 256, 0, stream>>>(qkv, Vt, ybf);
    // out = y @ W_proj   (M=8192, N=1024, K=1024), fp32 out
    gemm_bt<false><<<dim3(8, 64), 256, 0, stream>>>(ybf, WpT, nullptr, out, 8192, 1024, 1024);
}

// Round 18
// 170.303 us; speedup vs baseline: 1.6152x; 1.0058x over previous
//
#include <hip/hip_runtime.h>
#include <hip/hip_bf16.h>

typedef __bf16 bf16x8 __attribute__((ext_vector_type(8)));
typedef float f32x4 __attribute__((ext_vector_type(4)));

static __device__ __forceinline__ __bf16 tobf(float x) {
    __hip_bfloat16 h = __float2bfloat16(x);
    __bf16 r;
    __builtin_memcpy(&r, &h, 2);
    return r;
}

static __device__ __forceinline__ unsigned short tobits(float x) {
    __hip_bfloat16 h = __float2bfloat16(x);
    unsigned short u;
    __builtin_memcpy(&u, &h, 2);
    return u;
}

// fast 2^x: single v_exp_f32 (no libm range-fixup code)
static __device__ __forceinline__ float fexp2(float x) {
    float r;
    asm("v_exp_f32 %0, %1" : "=v"(r) : "v"(x));
    return r;
}

// ---------------------------------------------------------------------------
// Fused prep: (a) x fp32 -> bf16 (vectorized), (b) W_attn^T with qscale
// folded into Q columns, (c) W_proj^T.  One launch instead of three.
// ---------------------------------------------------------------------------
__global__ __launch_bounds__(256) void prep_k(const float* __restrict__ x,
                                              __hip_bfloat16* __restrict__ x_bf,
                                              const float* __restrict__ Wa,
                                              __hip_bfloat16* __restrict__ WaT,
                                              const float* __restrict__ Wp,
                                              __hip_bfloat16* __restrict__ WpT) {
    __shared__ float tile[32][33];
    const int bid = blockIdx.x;
    const int tid = threadIdx.x;
    if (bid < 8192) {
        int i = bid * 256 + tid;
        float4 v = reinterpret_cast<const float4*>(x)[i];
        __hip_bfloat16 a = __float2bfloat16(v.x);
        __hip_bfloat16 b = __float2bfloat16(v.y);
        __hip_bfloat16 c = __float2bfloat16(v.z);
        __hip_bfloat16 d = __float2bfloat16(v.w);
        ushort4 o;
        o.x = *reinterpret_cast<unsigned short*>(&a);
        o.y = *reinterpret_cast<unsigned short*>(&b);
        o.z = *reinterpret_cast<unsigned short*>(&c);
        o.w = *reinterpret_cast<unsigned short*>(&d);
        reinterpret_cast<ushort4*>(x_bf)[i] = o;
        return;
    }
    const float* in;
    __hip_bfloat16* out;
    int bx, Cn, qrows;
    float qscale;
    int t;
    if (bid < 8192 + 3072) {
        t = bid - 8192;
        in = Wa; out = WaT; Cn = 3072; qrows = 1024;
        qscale = 0.045084223f;  // log2(e)/sqrt(1024)
        bx = t % 96;
    } else {
        t = bid - 11264;
        in = Wp; out = WpT; Cn = 1024; qrows = 0;
        qscale = 1.0f;
        bx = t % 32;
    }
    const int by = (bid < 11264) ? (t / 96) : (t / 32);
    const int R = 1024;
    const int c0 = bx * 32, r0 = by * 32;
    const int tx = tid & 31, ty = tid >> 5;  // 32 x 8
#pragma unroll
    for (int i = 0; i < 4; ++i)
        tile[ty + i * 8][tx] = in[(size_t)(r0 + ty + i * 8) * Cn + c0 + tx];
    __syncthreads();
#pragma unroll
    for (int i = 0; i < 4; ++i) {
        int orow = c0 + ty + i * 8;
        float v = tile[tx][ty + i * 8];
        if (orow < qrows) v *= qscale;
        out[(size_t)orow * R + r0 + tx] = __float2bfloat16(v);
    }
}

// ---------------------------------------------------------------------------
// bf16 GEMM, C = A[M][K] * B, with B given transposed: Bt[N][K].
// 128x128 tile, BK=64, chunk-XOR swizzle, zero bank conflicts. XCD swizzle.
// FUSE_VT: for GEMM1, V-section columns (bn >= 16) are written ONLY to the
// key-permuted Vt layout (transpose fused into the epilogue; packed 8-B
// stores since slot's low 2 bits equal the acc j index). Saves the separate
// vtrans pass and the qkv V-section write.
// ---------------------------------------------------------------------------
template <bool OUT_BF16, bool FUSE_VT>
__global__ __launch_bounds__(256) void gemm_bt(const __hip_bfloat16* __restrict__ A,
                                               const __hip_bfloat16* __restrict__ Bt,
                                               __hip_bfloat16* __restrict__ Cb,
                                               float* __restrict__ Cf,
                                               __hip_bfloat16* __restrict__ VtOut,
                                               int M, int N, int K) {
    __shared__ __attribute__((aligned(16))) char As[128 * 128];  // bf16 [128 rows][64 k]
    __shared__ __attribute__((aligned(16))) char Bs[128 * 128];
    const int tid = threadIdx.x;
    const int lane = tid & 63, wid = tid >> 6;
    const int l15 = lane & 15, lg = lane >> 4;
    const int wr = wid >> 1, wc = wid & 1;
    const int lin = blockIdx.y * gridDim.x + blockIdx.x;
    const int cpx = (gridDim.x * gridDim.y) >> 3;
    const int sw = (lin & 7) * cpx + (lin >> 3);
    const int bn = sw % gridDim.x, bm = sw / gridDim.x;
    const size_t arow0 = (size_t)bm * 128;
    const size_t brow0 = (size_t)bn * 128;

    f32x4 acc[4][4] = {};

    const int nk = K >> 6;
    for (int kt = 0; kt < nk; ++kt) {
        __syncthreads();
        {
            const int k0 = kt * 64;
#pragma unroll
            for (int p = 0; p < 4; ++p) {
                int idx = p * 256 + tid;
                int row = idx >> 3;
                int c = idx & 7;
                int col = 8 * (c ^ (row & 7));  // pre-swizzled source chunk
                const __hip_bfloat16* ga = A + (arow0 + row) * (size_t)K + k0 + col;
                const __hip_bfloat16* gb = Bt + (brow0 + row) * (size_t)K + k0 + col;
                __builtin_amdgcn_global_load_lds(
                    (const __attribute__((address_space(1))) void*)ga,
                    (__attribute__((address_space(3))) void*)(&As[idx * 16]), 16, 0, 0);
                __builtin_amdgcn_global_load_lds(
                    (const __attribute__((address_space(1))) void*)gb,
                    (__attribute__((address_space(3))) void*)(&Bs[idx * 16]), 16, 0, 0);
            }
        }
        __syncthreads();
        const int swz = l15 & 7;
#pragma unroll
        for (int ks = 0; ks < 2; ++ks) {
            bf16x8 af[4], bfr[4];
#pragma unroll
            for (int m = 0; m < 4; ++m)
                af[m] = *reinterpret_cast<const bf16x8*>(
                    &As[(wr * 64 + m * 16 + l15) * 128 + 16 * ((ks * 4 + lg) ^ swz)]);
#pragma unroll
            for (int n = 0; n < 4; ++n)
                bfr[n] = *reinterpret_cast<const bf16x8*>(
                    &Bs[(wc * 64 + n * 16 + l15) * 128 + 16 * ((ks * 4 + lg) ^ swz)]);
#pragma unroll
            for (int m = 0; m < 4; ++m)
#pragma unroll
                for (int n = 0; n < 4; ++n)
                    acc[m][n] = __builtin_amdgcn_mfma_f32_16x16x32_bf16(af[m], bfr[n], acc[m][n], 0, 0, 0);
        }
    }

    if (FUSE_VT && bn >= 16) {
        // V-section: write transposed + key-permuted directly into Vt.
        // row = b*2048 + t; vt_row = b*1024 + (col - 2048);
        // dst elem = vt_row*2048 + (t>>5)*32 + slot, slot low 2 bits = j.
#pragma unroll
        for (int m = 0; m < 4; ++m) {
            const int rowbase = bm * 128 + wr * 64 + m * 16 + lg * 4;
            const int bq = rowbase >> 11;
            const int t = rowbase & 2047;
            const int tt = t >> 5, r0 = t & 31;
            const int slotbase = ((r0 & 12) << 1) | ((r0 >> 4) << 2);
#pragma unroll
            for (int n = 0; n < 4; ++n) {
                const int col = bn * 128 + wc * 64 + n * 16 + l15;
                const size_t vrow = (size_t)bq * 1024 + (col - 2048);
                uint2 u;
                u.x = (unsigned)tobits(acc[m][n][0]) | ((unsigned)tobits(acc[m][n][1]) << 16);
                u.y = (unsigned)tobits(acc[m][n][2]) | ((unsigned)tobits(acc[m][n][3]) << 16);
                *reinterpret_cast<uint2*>(&VtOut[vrow * 2048 + tt * 32 + slotbase]) = u;
            }
        }
        return;
    }

#pragma unroll
    for (int m = 0; m < 4; ++m) {
#pragma unroll
        for (int n = 0; n < 4; ++n) {
#pragma unroll
            for (int j = 0; j < 4; ++j) {
                int row = bm * 128 + wr * 64 + m * 16 + lg * 4 + j;
                int col = bn * 128 + wc * 64 + n * 16 + l15;
                if (OUT_BF16)
                    Cb[(size_t)row * N + col] = __float2bfloat16(acc[m][n][j]);
                else
                    Cf[(size_t)row * N + col] = acc[m][n][j];
            }
        }
    }
}

// ---------------------------------------------------------------------------
// Flash attention (causal), swapped-QK^T, key-permuted V, MAX-FREE softmax,
// MFMA ROW-SUM, 4-WAVE BLOCKS, triangle-paired 2-pass blocks, 3-BUFFER
// K/V ROTATION with COUNTED vmcnt: tile kt+2 staged during tile kt; the
// end-of-tile wait is vmcnt(4) (drains only the kt+1 stage issued a full
// iteration earlier; the just-issued loads stay in flight across the
// barrier). Grid (bh=64, y=8); 36 tile-iterations per block for every y.
// ---------------------------------------------------------------------------
__global__ __launch_bounds__(256) void attn_k(const __hip_bfloat16* __restrict__ qkv,
                                              const __hip_bfloat16* __restrict__ Vt,
                                              __hip_bfloat16* __restrict__ y) {
    constexpr int TT = 2048;
    constexpr int S3C = 3072;
    const int bh = blockIdx.x, b = bh >> 4, h = bh & 15;
    const int tid = threadIdx.x;
    const int wid = tid >> 6, lane = tid & 63;
    const int l15 = lane & 15, lg = lane >> 4;

    __shared__ __attribute__((aligned(16))) char Ks[3][64 * 128];  // [key][d-chunk^swz]
    __shared__ __attribute__((aligned(16))) char Vs[3][64 * 128];  // [d][key-chunk^swz]

    const __hip_bfloat16* base = qkv + (size_t)b * TT * S3C;
    const int qo = h * 64, ko = 1024 + h * 64;
    const __hip_bfloat16* vt = Vt + (size_t)bh * 64 * TT;

    // B-fragment of ones for the MFMA row-sum
    bf16x8 vones;
#pragma unroll
    for (int i = 0; i < 8; ++i) vones[i] = tobf(1.0f);

    // staging unit geometry: 2 x 16B units per thread for K and V each
    const int idx0 = tid, idx1 = 256 + tid;
    const int r0 = idx0 >> 3, c0 = 8 * ((idx0 & 7) ^ (r0 & 7));
    const int r1 = idx1 >> 3, c1 = 8 * ((idx1 & 7) ^ (r1 & 7));

#pragma unroll 1
    for (int pass = 0; pass < 2; ++pass) {
        const int st = pass == 0 ? (15 - (int)blockIdx.y) : (int)blockIdx.y;
        const int qbase = st * 128 + wid * 32;
        const int my_nt = (qbase >> 6) + 1;  // tiles this wave computes
        const int blk_nt = st * 2 + 2;       // tiles the block stages

        // Q B-fragments (pre-scaled by log2e/sqrt(C)): [m][half]
        bf16x8 aq[2][2];
#pragma unroll
        for (int m = 0; m < 2; ++m) {
            const __hip_bfloat16* qp = base + (size_t)(qbase + m * 16 + l15) * S3C + qo + lg * 8;
            aq[m][0] = *reinterpret_cast<const bf16x8*>(qp);
            aq[m][1] = *reinterpret_cast<const bf16x8*>(qp + 32);
        }

        f32x4 acc[2][4] = {};  // [m][dg]: row=q(lg*4+j), col=d(dg*16+l15)
        f32x4 lsum[2] = {};    // MFMA row-sums, same row layout as acc

        // hoisted staging source pointers (advance by constant stride/call)
        const __hip_bfloat16* kp0 = base + (size_t)r0 * S3C + ko + c0;
        const __hip_bfloat16* kp1 = base + (size_t)r1 * S3C + ko + c1;
        const __hip_bfloat16* vp0 = vt + (size_t)r0 * TT + c0;
        const __hip_bfloat16* vp1 = vt + (size_t)r1 * TT + c1;

        auto stage = [&](int buf) {
            char* Kd = &Ks[buf][0];
            char* Vd = &Vs[buf][0];
            __builtin_amdgcn_global_load_lds(
                (const __attribute__((address_space(1))) void*)kp0,
                (__attribute__((address_space(3))) void*)(Kd + idx0 * 16), 16, 0, 0);
            __builtin_amdgcn_global_load_lds(
                (const __attribute__((address_space(1))) void*)kp1,
                (__attribute__((address_space(3))) void*)(Kd + idx1 * 16), 16, 0, 0);
            __builtin_amdgcn_global_load_lds(
                (const __attribute__((address_space(1))) void*)vp0,
                (__attribute__((address_space(3))) void*)(Vd + idx0 * 16), 16, 0, 0);
            __builtin_amdgcn_global_load_lds(
                (const __attribute__((address_space(1))) void*)vp1,
                (__attribute__((address_space(3))) void*)(Vd + idx1 * 16), 16, 0, 0);
            kp0 += (size_t)64 * S3C;
            kp1 += (size_t)64 * S3C;
            vp0 += 64;
            vp1 += 64;
        };

        // prologue: tiles 0,1 staged; vmcnt(4) drains tile 0 (+ Q loads)
        stage(0);
        stage(1);
        asm volatile("s_waitcnt vmcnt(4)" ::: "memory");
        __syncthreads();

        int bc = 0;
        for (int kt = 0; kt < blk_nt; ++kt) {
            const bool more = (kt + 2 < blk_nt);
            if (more) {
                int bs = bc + 2;
                if (bs >= 3) bs -= 3;
                stage(bs);
            }
            if (kt < my_nt) {
                const int kb = kt * 64;
                const char* Kb = &Ks[bc][0];
                const char* Vb = &Vs[bc][0];
                const int swl = l15 & 7;
                // ---- QK^T (swapped): s[m][cg][j] = S[key=kb+16cg+4lg+j][q=qbase+16m+l15]
                f32x4 s[2][4];
                __builtin_amdgcn_s_setprio(1);
#pragma unroll
                for (int cg = 0; cg < 4; ++cg) {
                    const char* krow = Kb + (cg * 16 + l15) * 128;
                    bf16x8 k0 = *reinterpret_cast<const bf16x8*>(krow + 16 * (lg ^ swl));
                    bf16x8 k1 = *reinterpret_cast<const bf16x8*>(krow + 16 * ((4 + lg) ^ swl));
#pragma unroll
                    for (int m = 0; m < 2; ++m) {
                        f32x4 z = {0.f, 0.f, 0.f, 0.f};
                        z = __builtin_amdgcn_mfma_f32_16x16x32_bf16(k0, aq[m][0], z, 0, 0, 0);
                        z = __builtin_amdgcn_mfma_f32_16x16x32_bf16(k1, aq[m][1], z, 0, 0, 0);
                        s[m][cg] = z;
                    }
                }
                __builtin_amdgcn_s_setprio(0);
                // ---- V B-frags from shared LDS (conflict-free pattern)
                bf16x8 vb[2][4];
#pragma unroll
                for (int dg = 0; dg < 4; ++dg) {
                    const char* vrow = Vb + (dg * 16 + l15) * 128;
                    vb[0][dg] = *reinterpret_cast<const bf16x8*>(vrow + 16 * (lg ^ swl));
                    vb[1][dg] = *reinterpret_cast<const bf16x8*>(vrow + 16 * ((4 + lg) ^ swl));
                }
                // ---- max-free softmax: p = 2^s (masked -> 0)
                float p[2][4][4];
                const bool needmask = (kb + 63 > qbase);
#pragma unroll
                for (int m = 0; m < 2; ++m)
#pragma unroll
                    for (int cg = 0; cg < 4; ++cg)
#pragma unroll
                        for (int j = 0; j < 4; ++j) {
                            float e = fexp2(s[m][cg][j]);
                            if (needmask) {
                                int key = kb + cg * 16 + lg * 4 + j;
                                int qrow = qbase + m * 16 + l15;
                                e = (key > qrow) ? 0.f : e;
                            }
                            p[m][cg][j] = e;
                        }
                // ---- P A-frags: pure register pack (key-permute baked into Vt)
                bf16x8 pa[2][2];
#pragma unroll
                for (int m = 0; m < 2; ++m)
#pragma unroll
                    for (int ks = 0; ks < 2; ++ks) {
                        bf16x8 tt2;
                        tt2[0] = tobf(p[m][2 * ks][0]);
                        tt2[1] = tobf(p[m][2 * ks][1]);
                        tt2[2] = tobf(p[m][2 * ks][2]);
                        tt2[3] = tobf(p[m][2 * ks][3]);
                        tt2[4] = tobf(p[m][2 * ks + 1][0]);
                        tt2[5] = tobf(p[m][2 * ks + 1][1]);
                        tt2[6] = tobf(p[m][2 * ks + 1][2]);
                        tt2[7] = tobf(p[m][2 * ks + 1][3]);
                        pa[m][ks] = tt2;
                    }
                // ---- PV + MFMA row-sum
                __builtin_amdgcn_s_setprio(1);
#pragma unroll
                for (int ks = 0; ks < 2; ++ks) {
#pragma unroll
                    for (int dg = 0; dg < 4; ++dg)
#pragma unroll
                        for (int m = 0; m < 2; ++m)
                            acc[m][dg] = __builtin_amdgcn_mfma_f32_16x16x32_bf16(
                                pa[m][ks], vb[ks][dg], acc[m][dg], 0, 0, 0);
#pragma unroll
                    for (int m = 0; m < 2; ++m)
                        lsum[m] = __builtin_amdgcn_mfma_f32_16x16x32_bf16(pa[m][ks], vones,
                                                                          lsum[m], 0, 0, 0);
                }
                __builtin_amdgcn_s_setprio(0);
            }
            // counted wait: only drain the stage issued one iteration ago
            if (more)
                asm volatile("s_waitcnt vmcnt(4)" ::: "memory");
            else
                asm volatile("s_waitcnt vmcnt(0)" ::: "memory");
            __syncthreads();
            bc = (bc == 2) ? 0 : bc + 1;
        }

        // ---- epilogue: lsum already in acc row layout -> no cross-lane ops
#pragma unroll
        for (int m = 0; m < 2; ++m)
#pragma unroll
            for (int j = 0; j < 4; ++j) {
                float inv = 1.f / lsum[m][j];
                int t = qbase + m * 16 + lg * 4 + j;
#pragma unroll
                for (int dg = 0; dg < 4; ++dg) {
                    float o = acc[m][dg][j] * inv;
                    y[((size_t)(b * TT + t)) * 1024 + h * 64 + dg * 16 + l15] = __float2bfloat16(o);
                }
            }
        // pass isolation: all staging drained (vmcnt(0) on last iter) + barrier
        __syncthreads();
    }
}

// ---------------------------------------------------------------------------
extern "C" void kernel_launch(void* const* d_in, const int* in_sizes, int n_in,
                              void* d_out, int out_size, void* d_ws, size_t ws_size,
                              hipStream_t stream) {
    const float* x = (const float*)d_in[0];   // [4,2048,1024]
    const float* Wa = (const float*)d_in[1];  // [1024,3072]
    const float* Wp = (const float*)d_in[2];  // [1024,1024]
    float* out = (float*)d_out;               // [4,2048,1024] fp32

    __hip_bfloat16* ws = (__hip_bfloat16*)d_ws;
    __hip_bfloat16* x_bf = ws;                          // 8192*1024 (dead after GEMM1)
    __hip_bfloat16* WaT = x_bf + (size_t)8192 * 1024;   // 3072*1024 (W_attn^T)
    __hip_bfloat16* WpT = WaT + (size_t)3072 * 1024;    // 1024*1024 (W_proj^T)
    __hip_bfloat16* qkv = WpT + (size_t)1024 * 1024;    // 8192*3072 (V third unused)
    __hip_bfloat16* ybf = qkv + (size_t)8192 * 3072;    // 8192*1024
    __hip_bfloat16* Vt = ybf + (size_t)8192 * 1024;     // 64*64*2048 = 8192*1024

    // fused prep: x cvt + W_attn^T (Q cols scaled by log2e/sqrt(C)) + W_proj^T
    prep_k<<<8192 + 3072 + 1024, 256, 0, stream>>>(x, x_bf, Wa, WaT, Wp, WpT);
    // qkv = x @ W_attn (M=8192, N=3072, K=1024); V columns fused into Vt
    gemm_bt<true, true><<<dim3(24, 64), 256, 0, stream>>>(x_bf, WaT, qkv, nullptr, Vt,
                                                          8192, 3072, 1024);
    // flash attention -> ybf (4-wave triangle-paired blocks, 3-buf staging)
    attn_k<<<dim3(64, 8), 256, 0, stream>>>(qkv, Vt, ybf);
    // out = y @ W_proj   (M=8192, N=1024, K=1024), fp32 out
    gemm_bt<false, false><<<dim3(8, 64), 256, 0, stream>>>(ybf, WpT, nullptr, out, nullptr,
                                                           8192, 1024, 1024);
}